// Round 5
// baseline (564.917 us; speedup 1.0000x reference)
//
#include <hip/hip_runtime.h>

typedef __bf16 bf16;
typedef bf16 bf16x8 __attribute__((ext_vector_type(8)));
typedef bf16 bf16x4 __attribute__((ext_vector_type(4)));
typedef float f32x4 __attribute__((ext_vector_type(4)));

#define C_DIM 1024
#define T_DIM 2048
#define B_DIM 4
#define H_DIM 4096

// ---------------------------------------------------------------------------
// async global -> LDS, 16B per lane. LDS dest is wave-uniform base + lane*16.
// ---------------------------------------------------------------------------
__device__ inline void gld_lds16(const bf16* g, bf16* l) {
    __builtin_amdgcn_global_load_lds(
        (const __attribute__((address_space(1))) unsigned int*)g,
        (__attribute__((address_space(3))) unsigned int*)l,
        16, 0, 0);
}

// fast tanh-gelu: u * sigmoid(1.5957692*u + 0.07135481*u^3)
__device__ inline float fast_gelu(float u) {
    float k2 = 1.5957691216057308f * u + 0.07135480895843475f * u * u * u;
    float t = __expf(-k2);
    return u * __builtin_amdgcn_rcpf(1.0f + t);
}

// ---------------------------------------------------------------------------
// Read-ahead pipelined GEMM: C = alpha*A[M,K]@Bt[N,K]^T (+bias)(+gelu|+resid)
//
// BM=256, BN in {256,128}, 8 waves, 512 threads, MFMA 16x16x32 bf16.
// One phase = one 32-wide k-step. Slot s(τ)=τ&3 in a 4-slot LDS ring
// (A [4][256][32] = 64KB, B [4][BN][32]).
//
// Phase p body:
//   { ds_read frags for p+1 (into OTHER parity reg set) | stage slot for
//     k-step p+3 | sched_barrier | BAR1 | MFMA(p) (compiler lgkm-waits only
//     p's frags; p+1 reads SERVICE DURING MFMA) | vmcnt(g) | BAR2 }
// Window overlap is the point: R4's structure serialized LDS-window and
// MFMA-window across the barriered CU (MfmaUtil 31%); register double-buffer
// lets LDS service hide under MFMA.
//
// Slot lifetime (race-checked): s staged @tau-3, ds_read @tau-1, MFMA @tau,
// restaged @tau+1. WAR safe: reads@tau-1 are proven serviced by the lgkm-wait
// before MFMA(tau) which precedes BAR2(tau), which precedes restage@tau+1.
// Cross-wave publication: vmcnt(g) BEFORE BAR2 (m201 placement) => passing
// BAR2(q-1) proves ALL waves' stages through q-2 landed => reads@q safe.
// Tail ladder: VMC(g)...VMC(g), VMC(0) at phase NP-3, none after.
//
// XOR swizzle (verified R2: SQ_LDS_BANK_CONFLICT = 0): 16B chunk c of row r
// stored at slot c ^ ((r>>1)&3); read chunk = lc ^ ((lr>>1)&3) (free, folds
// into base); gld_lds dest stays LINEAR, global SOURCE chunk pre-swizzled.
// NO XCD swizzle (R3: 3.6x FETCH blowup).
// ---------------------------------------------------------------------------
template <int EPI, typename OutT, int BN>
__launch_bounds__(512, 2)
__global__ void gemm8p(const bf16* __restrict__ A, int lda, long long sA,
                       const bf16* __restrict__ Bt, int ldb, long long sB,
                       OutT* __restrict__ Cout, int ldc, long long sC,
                       const float* __restrict__ bias,
                       const float* __restrict__ resid, long long sR,
                       float alpha, int K) {
    constexpr int BQ = BN / 128;            // gld_lds issues per B slot
    constexpr int FM = (BN == 256) ? 8 : 4; // row fragments per wave
    constexpr int AW = (BN == 256) ? 128 : 64;  // rows per wave strip

    const int z = blockIdx.z;
    A += (long long)z * sA;
    Bt += (long long)z * sB;
    Cout += (long long)z * sC;
    if (resid) resid += (long long)z * sR;

    const int rowBase = blockIdx.x * 256;
    const int colBase = blockIdx.y * BN;

    __shared__ __align__(16) bf16 As[4 * 256 * 32];
    __shared__ __align__(16) bf16 Bs[4 * BN * 32];

    const int tid = threadIdx.x;
    const int w = tid >> 6;
    const int lane = tid & 63;
    const int wm = (BN == 256) ? (w >> 2) : (w >> 1);
    const int wn = (BN == 256) ? (w & 3) : (w & 1);
    const int lr = lane & 15, lc = lane >> 4;

    // staging: lane covers (row = tid>>2, swizzled 16B chunk) of a 128-row slab
    const int gchunk = (tid & 3) ^ ((tid >> 3) & 3);
    const bf16* Ag = A + (size_t)(rowBase + (tid >> 2)) * lda + gchunk * 8;
    const bf16* Bg = Bt + (size_t)(colBase + (tid >> 2)) * ldb + gchunk * 8;
    const size_t ldaL = (size_t)lda, ldbL = (size_t)ldb;
    bf16* AsW = As + w * 512;   // wave slice inside each staged 8KB half-slab
    bf16* BsW = Bs + w * 512;

    // fragment read bases (element offsets); read chunk XOR folds into base
    const int rchunk = lc ^ ((lr >> 1) & 3);
    const int aBase = wm * (AW * 32) + lr * 32 + rchunk * 8;
    const int bBase = wn * 2048 + lr * 32 + rchunk * 8;

// stage k-step tau into its ring slot (tau&3)
#define STAGE(slot, tau) do {                                              \
        const bf16* _ga = Ag + (size_t)(tau) * 32;                         \
        bf16* _la = AsW + (slot) * 8192;                                   \
        gld_lds16(_ga, _la);                                               \
        gld_lds16(_ga + 128 * ldaL, _la + 4096);                           \
        const bf16* _gb = Bg + (size_t)(tau) * 32;                         \
        bf16* _lb = BsW + (slot) * (BN * 32);                              \
        gld_lds16(_gb, _lb);                                               \
        if constexpr (BQ == 2) gld_lds16(_gb + 128 * ldbL, _lb + 4096);    \
    } while (0)

#define LOAD_AB(afd, bvd, slot) do {                                       \
        _Pragma("unroll")                                                  \
        for (int i = 0; i < FM; i++)                                       \
            afd[i] = *(const bf16x8*)(As + aBase + (slot) * 8192 + i * 512); \
        _Pragma("unroll")                                                  \
        for (int j = 0; j < 4; j++)                                        \
            bvd[j] = *(const bf16x8*)(Bs + bBase + (slot) * (BN * 32) + j * 512); \
    } while (0)

#define MMA(afs, bvs) do {                                                 \
        __builtin_amdgcn_s_setprio(1);                                     \
        _Pragma("unroll")                                                  \
        for (int i = 0; i < FM; i++)                                       \
            _Pragma("unroll")                                              \
            for (int j = 0; j < 4; j++)                                    \
                acc[i][j] = __builtin_amdgcn_mfma_f32_16x16x32_bf16(       \
                    afs[i], bvs[j], acc[i][j], 0, 0, 0);                   \
        __builtin_amdgcn_s_setprio(0);                                     \
    } while (0)

#define SB() __builtin_amdgcn_sched_barrier(0)
#define BAR() __builtin_amdgcn_s_barrier()
#define VMCG() do {                                                        \
        if constexpr (BN == 256) asm volatile("s_waitcnt vmcnt(4)" ::: "memory"); \
        else                     asm volatile("s_waitcnt vmcnt(3)" ::: "memory"); \
    } while (0)
#define VMC0() asm volatile("s_waitcnt vmcnt(0)" ::: "memory")

    f32x4 acc[FM][4] = {};
    bf16x8 af0[FM], af1[FM], bv0[4], bv1[4];

    const int NP = K >> 5;  // 32-wide k-steps; K in {1024,2048,4096} -> NP % 4 == 0

    // ---- prologue: stage k-steps 0,1,2; publish; preload frags(0) ----
    STAGE(0, 0);
    STAGE(1, 1);
    STAGE(2, 2);
    VMCG();        // own slices of k-steps 0,1 landed (k-step 2 in flight)
    BAR();         // publish: all waves' 0,1 landed
    LOAD_AB(af0, bv0, 0);

    for (int kt = 0; kt < NP - 4; kt += 4) {
        // phase kt+0: MFMA slot0-parity0; read slot1->regs1; stage kt+3 (slot3)
        LOAD_AB(af1, bv1, 1);
        STAGE(3, kt + 3);
        SB(); BAR();
        MMA(af0, bv0);
        VMCG(); BAR();
        // phase kt+1
        LOAD_AB(af0, bv0, 2);
        STAGE(0, kt + 4);
        SB(); BAR();
        MMA(af1, bv1);
        VMCG(); BAR();
        // phase kt+2
        LOAD_AB(af1, bv1, 3);
        STAGE(1, kt + 5);
        SB(); BAR();
        MMA(af0, bv0);
        VMCG(); BAR();
        // phase kt+3
        LOAD_AB(af0, bv0, 0);
        STAGE(2, kt + 6);
        SB(); BAR();
        MMA(af1, bv1);
        VMCG(); BAR();
    }

    // ---- final 4 phases (kt = NP-4): last stage is k-step NP-1 ----
    LOAD_AB(af1, bv1, 1);
    STAGE(3, NP - 1);
    SB(); BAR();
    MMA(af0, bv0);
    VMCG(); BAR();

    LOAD_AB(af0, bv0, 2);
    SB(); BAR();
    MMA(af1, bv1);
    VMC0(); BAR();

    LOAD_AB(af1, bv1, 3);
    SB(); BAR();
    MMA(af0, bv0);
    BAR();

    MMA(af1, bv1);

#undef STAGE
#undef LOAD_AB
#undef MMA
#undef SB
#undef BAR
#undef VMCG
#undef VMC0

    // ---- epilogue. C/D layout (16x16x32): col = lane&15, row = (lane>>4)*4 + reg ----
    float bval[4];
#pragma unroll
    for (int j = 0; j < 4; j++)
        bval[j] = bias ? bias[colBase + wn * 64 + j * 16 + lr] : 0.0f;

#pragma unroll
    for (int fi = 0; fi < FM; fi++) {
        const int row = rowBase + wm * AW + fi * 16 + lc * 4;
#pragma unroll
        for (int fj = 0; fj < 4; fj++) {
            const int col = colBase + wn * 64 + fj * 16 + lr;
#pragma unroll
            for (int r = 0; r < 4; r++) {
                float v = acc[fi][fj][r] * alpha + bval[fj];
                if constexpr (EPI == 1) v = fast_gelu(v);
                if constexpr (EPI == 2) v += resid[(size_t)(row + r) * ldc + col];
                Cout[(size_t)(row + r) * ldc + col] = (OutT)v;
            }
        }
    }
}

// ---------------------------------------------------------------------------
// LayerNorm over last dim (C=1024), fp32 in -> bf16 out. One block per row.
// ---------------------------------------------------------------------------
__launch_bounds__(256)
__global__ void ln_kernel(const float* __restrict__ x, const float* __restrict__ g,
                          const float* __restrict__ b, bf16* __restrict__ out) {
    __shared__ float red[4];
    const int row = blockIdx.x;
    const int tid = threadIdx.x;
    const float4* xr = (const float4*)(x + (size_t)row * C_DIM);
    float4 v = xr[tid];
    float s = v.x + v.y + v.z + v.w;
#pragma unroll
    for (int m = 32; m; m >>= 1) s += __shfl_xor(s, m, 64);
    if ((tid & 63) == 0) red[tid >> 6] = s;
    __syncthreads();
    const float mu = (red[0] + red[1] + red[2] + red[3]) * (1.0f / C_DIM);
    const float dx = v.x - mu, dy = v.y - mu, dz = v.z - mu, dw = v.w - mu;
    float q = dx * dx + dy * dy + dz * dz + dw * dw;
#pragma unroll
    for (int m = 32; m; m >>= 1) q += __shfl_xor(q, m, 64);
    __syncthreads();
    if ((tid & 63) == 0) red[tid >> 6] = q;
    __syncthreads();
    const float var = (red[0] + red[1] + red[2] + red[3]) * (1.0f / C_DIM);
    const float rs = rsqrtf(var + 1e-5f);
    const float4 gg = ((const float4*)g)[tid];
    const float4 bb = ((const float4*)b)[tid];
    bf16x4 o;
    o[0] = (bf16)(dx * rs * gg.x + bb.x);
    o[1] = (bf16)(dy * rs * gg.y + bb.y);
    o[2] = (bf16)(dz * rs * gg.z + bb.z);
    o[3] = (bf16)(dw * rs * gg.w + bb.w);
    ((bf16x4*)(out + (size_t)row * C_DIM))[tid] = o;
}

// ---------------------------------------------------------------------------
// Row softmax: S row (T=2048 bf16) -> P row (bf16). One block per row.
// ---------------------------------------------------------------------------
__launch_bounds__(256)
__global__ void softmax_kernel(const bf16* __restrict__ S, bf16* __restrict__ P) {
    __shared__ float red[4];
    const size_t base = (size_t)blockIdx.x * T_DIM;
    const int tid = threadIdx.x;
    bf16x8 sv = ((const bf16x8*)(S + base))[tid];
    float e[8];
#pragma unroll
    for (int i = 0; i < 8; i++) e[i] = (float)sv[i];
    float mx = e[0];
#pragma unroll
    for (int i = 1; i < 8; i++) mx = fmaxf(mx, e[i]);
#pragma unroll
    for (int m = 32; m; m >>= 1) mx = fmaxf(mx, __shfl_xor(mx, m, 64));
    if ((tid & 63) == 0) red[tid >> 6] = mx;
    __syncthreads();
    mx = fmaxf(fmaxf(red[0], red[1]), fmaxf(red[2], red[3]));
    float s = 0.0f;
#pragma unroll
    for (int i = 0; i < 8; i++) {
        e[i] = __expf(e[i] - mx);
        s += e[i];
    }
#pragma unroll
    for (int m = 32; m; m >>= 1) s += __shfl_xor(s, m, 64);
    __syncthreads();
    if ((tid & 63) == 0) red[tid >> 6] = s;
    __syncthreads();
    const float inv = 1.0f / (red[0] + red[1] + red[2] + red[3]);
    bf16x8 p;
#pragma unroll
    for (int i = 0; i < 8; i++) p[i] = (bf16)(e[i] * inv);
    ((bf16x8*)(P + base))[tid] = p;
}

// ---------------------------------------------------------------------------
// Merged transpose+convert for all 4 weight matrices (fp32 [R,Cc] -> bf16 [Cc,R]).
// ---------------------------------------------------------------------------
__global__ void transpose_f2b_all(const float* __restrict__ s0, bf16* __restrict__ d0,
                                  const float* __restrict__ s1, bf16* __restrict__ d1,
                                  const float* __restrict__ s2, bf16* __restrict__ d2,
                                  const float* __restrict__ s3, bf16* __restrict__ d3) {
    __shared__ float tile[32][33];
    int id = blockIdx.x;
    const float* src;
    bf16* dst;
    int R, Cc, local;
    if (id < 3072)       { src = s0; dst = d0; R = 1024; Cc = 3072; local = id; }
    else if (id < 4096)  { src = s1; dst = d1; R = 1024; Cc = 1024; local = id - 3072; }
    else if (id < 8192)  { src = s2; dst = d2; R = 1024; Cc = 4096; local = id - 4096; }
    else                 { src = s3; dst = d3; R = 4096; Cc = 1024; local = id - 8192; }
    const int tilesX = Cc >> 5;
    const int bx = (local % tilesX) * 32;
    const int by = (local / tilesX) * 32;
    const int tx = threadIdx.x, ty = threadIdx.y;
    for (int i = ty; i < 32; i += 8)
        tile[i][tx] = src[(size_t)(by + i) * Cc + bx + tx];
    __syncthreads();
    for (int i = ty; i < 32; i += 8)
        dst[(size_t)(bx + i) * R + by + tx] = (bf16)tile[tx][i];
}

// Transpose bf16 [R, Cc] (ld=ldsrc) -> bf16 [Cc, R] (ld=R), batched via z.
__global__ void transpose_b2b(const bf16* __restrict__ src, int ldsrc, long long sstride,
                              bf16* __restrict__ dst, long long dstride, int R) {
    __shared__ bf16 tile[32][33];
    src += (long long)blockIdx.z * sstride;
    dst += (long long)blockIdx.z * dstride;
    const int bx = blockIdx.x * 32;
    const int by = blockIdx.y * 32;
    const int tx = threadIdx.x, ty = threadIdx.y;
    for (int i = ty; i < 32; i += 8)
        tile[i][tx] = src[(size_t)(by + i) * ldsrc + bx + tx];
    __syncthreads();
    for (int i = ty; i < 32; i += 8)
        dst[(size_t)(bx + i) * R + by + tx] = tile[tx][i];
}

// ---------------------------------------------------------------------------
extern "C" void kernel_launch(void* const* d_in, const int* in_sizes, int n_in,
                              void* d_out, int out_size, void* d_ws, size_t ws_size,
                              hipStream_t stream) {
    const float* x      = (const float*)d_in[0];
    const float* ln1_g  = (const float*)d_in[1];
    const float* ln1_b  = (const float*)d_in[2];
    const float* w_attn = (const float*)d_in[3];
    const float* b_attn = (const float*)d_in[4];
    const float* w_proj = (const float*)d_in[5];
    const float* b_proj = (const float*)d_in[6];
    const float* ln2_g  = (const float*)d_in[7];
    const float* ln2_b  = (const float*)d_in[8];
    const float* w_fc   = (const float*)d_in[9];
    const float* b_fc   = (const float*)d_in[10];
    const float* w_mlp  = (const float*)d_in[11];
    const float* b_mlp  = (const float*)d_in[12];
    float* out = (float*)d_out;

    const int M = B_DIM * T_DIM;  // 8192

    char* base = (char*)d_ws;
    size_t off = 0;
    auto alloc = [&](size_t bytes) -> char* {
        char* p = base + off;
        off += (bytes + 255) & ~(size_t)255;
        return p;
    };
    bf16* wT_attn = (bf16*)alloc((size_t)3072 * 1024 * 2);
    bf16* wT_proj = (bf16*)alloc((size_t)1024 * 1024 * 2);
    bf16* wT_fc   = (bf16*)alloc((size_t)4096 * 1024 * 2);
    bf16* wT_mlp  = (bf16*)alloc((size_t)1024 * 4096 * 2);
    bf16* h       = (bf16*)alloc((size_t)M * 1024 * 2);        // h1, reused as h2
    bf16* qkv     = (bf16*)alloc((size_t)M * 3072 * 2);
    bf16* vT      = (bf16*)alloc((size_t)B_DIM * 1024 * 2048 * 2);
    bf16* S       = (bf16*)alloc((size_t)B_DIM * 2048 * 2048 * 2);
    bf16* P       = (bf16*)alloc((size_t)B_DIM * 2048 * 2048 * 2);
    bf16* y       = (bf16*)alloc((size_t)M * 1024 * 2);
    float* x2     = (float*)alloc((size_t)M * 1024 * 4);
    bf16* act     = (bf16*)S;  // alias: S+P dead after PV; 67MB needed, S+P = 67MB

    const dim3 tb(32, 8);

    // weight transpose+convert, all 4 in one launch
    transpose_f2b_all<<<12288, tb, 0, stream>>>(w_attn, wT_attn, w_proj, wT_proj,
                                                w_fc, wT_fc, w_mlp, wT_mlp);

    // h = LN1(x)
    ln_kernel<<<M, 256, 0, stream>>>(x, ln1_g, ln1_b, h);

    // qkv = h @ w_attn + b_attn   [8192, 3072]
    gemm8p<0, bf16, 128><<<dim3(32, 24, 1), 512, 0, stream>>>(
        h, 1024, 0, wT_attn, 1024, 0, qkv, 3072, 0, b_attn, nullptr, 0, 1.0f, 1024);

    // vT[b] = v[b]^T   (v = qkv cols [2C,3C))
    transpose_b2b<<<dim3(1024 / 32, 2048 / 32, B_DIM), tb, 0, stream>>>(
        qkv + 2 * C_DIM, 3072, (long long)T_DIM * 3072, vT, (long long)C_DIM * T_DIM, T_DIM);

    // S[b] = q[b] @ k[b]^T * (1/32)   [2048, 2048] bf16
    gemm8p<0, bf16, 256><<<dim3(8, 8, B_DIM), 512, 0, stream>>>(
        qkv, 3072, (long long)T_DIM * 3072,
        qkv + C_DIM, 3072, (long long)T_DIM * 3072,
        S, 2048, (long long)T_DIM * T_DIM, nullptr, nullptr, 0, 0.03125f, 1024);

    // P = softmax(S) rows
    softmax_kernel<<<B_DIM * T_DIM, 256, 0, stream>>>(S, P);

    // y[b] = P[b] @ v[b]   [2048, 1024] bf16
    gemm8p<0, bf16, 128><<<dim3(8, 8, B_DIM), 512, 0, stream>>>(
        P, 2048, (long long)T_DIM * T_DIM,
        vT, 2048, (long long)C_DIM * T_DIM,
        y, 1024, (long long)T_DIM * C_DIM, nullptr, nullptr, 0, 1.0f, 2048);

    // x2 = y @ w_proj + b_proj + x   [8192, 1024] fp32
    gemm8p<2, float, 128><<<dim3(32, 8, 1), 512, 0, stream>>>(
        y, 1024, 0, wT_proj, 1024, 0, x2, 1024, 0, b_proj, x, 0, 1.0f, 1024);

    // h2 = LN2(x2)  (reuse h buffer)
    ln_kernel<<<M, 256, 0, stream>>>(x2, ln2_g, ln2_b, h);

    // act = gelu(h2 @ w_fc + b_fc)   [8192, 4096] bf16
    gemm8p<1, bf16, 256><<<dim3(32, 16, 1), 512, 0, stream>>>(
        h, 1024, 0, wT_fc, 1024, 0, act, 4096, 0, b_fc, nullptr, 0, 1.0f, 1024);

    // out = act @ w_mlp_proj + b_mlp_proj + x2   [8192, 1024] fp32
    gemm8p<2, float, 128><<<dim3(32, 8, 1), 512, 0, stream>>>(
        act, 4096, 0, wT_mlp, 4096, 0, out, 1024, 0, b_mlp, x2, 0, 1.0f, 4096);
}

// Round 6
// 516.360 us; speedup vs baseline: 1.0940x; 1.0940x over previous
//
#include <hip/hip_runtime.h>

typedef __bf16 bf16;
typedef bf16 bf16x8 __attribute__((ext_vector_type(8)));
typedef bf16 bf16x4 __attribute__((ext_vector_type(4)));
typedef float f32x4 __attribute__((ext_vector_type(4)));

#define C_DIM 1024
#define T_DIM 2048
#define B_DIM 4
#define H_DIM 4096

// ---------------------------------------------------------------------------
// async global -> LDS, 16B per lane. LDS dest is wave-uniform base + lane*16.
// ---------------------------------------------------------------------------
__device__ inline void gld_lds16(const bf16* g, bf16* l) {
    __builtin_amdgcn_global_load_lds(
        (const __attribute__((address_space(1))) unsigned int*)g,
        (__attribute__((address_space(3))) unsigned int*)l,
        16, 0, 0);
}

// fast tanh-gelu: u * sigmoid(1.5957692*u + 0.07135481*u^3)
__device__ inline float fast_gelu(float u) {
    float k2 = 1.5957691216057308f * u + 0.07135480895843475f * u * u * u;
    float t = __expf(-k2);
    return u * __builtin_amdgcn_rcpf(1.0f + t);
}

// ---------------------------------------------------------------------------
// 2-phase-per-K-tile 128x128 GEMM: C = alpha*A[M,K]@Bt[N,K]^T (+bias)(+gelu|+resid)
//
// BM=BN=128, BK=64, 4 waves (2x2), 256 threads, wave tile 64x64,
// MFMA 16x16x32 bf16, 16 MFMA/phase.  LDS 64KB total (A [2][2][128][32] 32KB
// + B same) -> 2 blocks/CU (vs R4's 96KB/1 block).  Two barrier domains per
// CU: when one block stalls in its vmcnt/barrier window the other block's
// MFMA burst feeds the matrix pipe (m114 cross-block overlap) ON TOP of the
// R4 intra-block pipeline.  R5's per-32k read-ahead REVERTED: it collapsed
// prefetch distance to ~1 phase (< HBM latency) and regressed 87->104us.
//
// Phase = { VMC | ds_read A-frags + B-frags of slot | stage one {A,B} slot |
//           BAR | setprio(1) 16xMFMA setprio(0) | BAR }.
// Slot lifetime: staged 3 phases before read; restaged 1 phase after read
// (WAR separated by lgkm-consume + BAR2).  g=4 gld/phase: steady VMC(8)
// (load issued >=2 phases ago landed), tail ladder 8/8/4/0.  Publication:
// every wave's VMC(p) precedes its BAR1(p); passing BAR2(p-1) proves all
// waves' stages through p-3 landed.
//
// XOR swizzle (verified R2: SQ_LDS_BANK_CONFLICT = 0): 16B chunk c of row r
// stored at slot c ^ ((r>>1)&3); read chunk = lc ^ ((lr>>1)&3) (lane-only,
// folds into base; valid since row = 64*wm + 16*i + lr ≡ lr mod 8);
// gld_lds dest stays LINEAR, global SOURCE chunk pre-swizzled.
// NO XCD swizzle (R3: 3.6x FETCH blowup).
// ---------------------------------------------------------------------------
template <int EPI, typename OutT>
__launch_bounds__(256, 2)
__global__ void gemm8p(const bf16* __restrict__ A, int lda, long long sA,
                       const bf16* __restrict__ Bt, int ldb, long long sB,
                       OutT* __restrict__ Cout, int ldc, long long sC,
                       const float* __restrict__ bias,
                       const float* __restrict__ resid, long long sR,
                       float alpha, int K) {
    const int z = blockIdx.z;
    A += (long long)z * sA;
    Bt += (long long)z * sB;
    Cout += (long long)z * sC;
    if (resid) resid += (long long)z * sR;

    const int rowBase = blockIdx.x * 128;
    const int colBase = blockIdx.y * 128;

    __shared__ __align__(16) bf16 As[2 * 2 * 128 * 32];
    __shared__ __align__(16) bf16 Bs[2 * 2 * 128 * 32];

    const int tid = threadIdx.x;
    const int w = tid >> 6;
    const int lane = tid & 63;
    const int wm = w >> 1, wn = w & 1;
    const int lr = lane & 15, lc = lane >> 4;

    // staging: lane covers (row = tid>>2 in 0..63, swizzled 16B chunk);
    // second gld per slot covers rows 64..127 (chunk swizzle row-invariant mod 8)
    const int gchunk = (tid & 3) ^ ((tid >> 3) & 3);
    const bf16* Ag = A + (size_t)(rowBase + (tid >> 2)) * lda + gchunk * 8;
    const bf16* Bg = Bt + (size_t)(colBase + (tid >> 2)) * ldb + gchunk * 8;
    const size_t ldaL = (size_t)lda, ldbL = (size_t)ldb;
    bf16* AsW = As + w * 512;   // wave slice inside each staged 4KB half-slab
    bf16* BsW = Bs + w * 512;

    // fragment read bases (element offsets); read chunk XOR folds into base
    const int rchunk = lc ^ ((lr >> 1) & 3);
    const int aBase = wm * 2048 + lr * 32 + rchunk * 8;   // + slot*4096 + i*512
    const int bBase = wn * 2048 + lr * 32 + rchunk * 8;

// stage {A,B} slot pair (buf,ks) with k-tile index tau (4 gld_lds)
#define STAGE(buf, ks, tau) do {                                           \
        const bf16* _ga = Ag + (size_t)(tau) * 64 + (ks) * 32;             \
        bf16* _la = AsW + ((buf) * 2 + (ks)) * 4096;                       \
        gld_lds16(_ga, _la);                                               \
        gld_lds16(_ga + 64 * ldaL, _la + 2048);                            \
        const bf16* _gb = Bg + (size_t)(tau) * 64 + (ks) * 32;             \
        bf16* _lb = BsW + ((buf) * 2 + (ks)) * 4096;                       \
        gld_lds16(_gb, _lb);                                               \
        gld_lds16(_gb + 64 * ldbL, _lb + 2048);                            \
    } while (0)

#define LOAD_AB(buf, ks) do {                                              \
        _Pragma("unroll")                                                  \
        for (int i = 0; i < 4; i++)                                        \
            af[i] = *(const bf16x8*)(As + aBase + ((buf) * 2 + (ks)) * 4096 \
                                     + i * 512);                           \
        _Pragma("unroll")                                                  \
        for (int j = 0; j < 4; j++)                                        \
            bfv[j] = *(const bf16x8*)(Bs + bBase + ((buf) * 2 + (ks)) * 4096 \
                                      + j * 512);                          \
    } while (0)

#define MMAALL() do {                                                      \
        __builtin_amdgcn_s_setprio(1);                                     \
        _Pragma("unroll")                                                  \
        for (int i = 0; i < 4; i++)                                        \
            _Pragma("unroll")                                              \
            for (int j = 0; j < 4; j++)                                    \
                acc[i][j] = __builtin_amdgcn_mfma_f32_16x16x32_bf16(       \
                    af[i], bfv[j], acc[i][j], 0, 0, 0);                    \
        __builtin_amdgcn_s_setprio(0);                                     \
    } while (0)

#define BAR() __builtin_amdgcn_s_barrier()
#define VMC(n) asm volatile("s_waitcnt vmcnt(" #n ")" ::: "memory")

    f32x4 acc[4][4] = {};
    bf16x8 af[4], bfv[4];

    const int NT = K >> 6;  // K in {1024,2048,4096} -> NT even, >= 16

    // ---- prologue: 3 slot pairs in read order (12 gld outstanding) ----
    STAGE(0, 0, 0);
    STAGE(0, 1, 0);
    STAGE(1, 0, 1);
    BAR();

    for (int t = 0; t < NT - 2; t += 2) {
        // ---- tile t (buf 0) ----
        VMC(8);
        LOAD_AB(0, 0);
        STAGE(1, 1, t + 1);
        BAR(); MMAALL(); BAR();

        VMC(8);
        LOAD_AB(0, 1);
        STAGE(0, 0, t + 2);
        BAR(); MMAALL(); BAR();

        // ---- tile t+1 (buf 1) ----
        VMC(8);
        LOAD_AB(1, 0);
        STAGE(0, 1, t + 2);
        BAR(); MMAALL(); BAR();

        VMC(8);
        LOAD_AB(1, 1);
        STAGE(1, 0, t + 3);
        BAR(); MMAALL(); BAR();
    }

    // ---- tail: tiles NT-2 (buf0), NT-1 (buf1); ladder 8/8/4/0 ----
    VMC(8);
    LOAD_AB(0, 0);
    STAGE(1, 1, NT - 1);
    BAR(); MMAALL(); BAR();

    VMC(8);
    LOAD_AB(0, 1);
    BAR(); MMAALL(); BAR();

    VMC(4);
    LOAD_AB(1, 0);
    BAR(); MMAALL(); BAR();

    VMC(0);
    LOAD_AB(1, 1);
    MMAALL();

#undef STAGE
#undef LOAD_AB
#undef MMAALL
#undef BAR
#undef VMC

    // ---- epilogue. C/D layout (16x16x32): col = lane&15, row = (lane>>4)*4 + reg ----
    float bval[4];
#pragma unroll
    for (int j = 0; j < 4; j++)
        bval[j] = bias ? bias[colBase + wn * 64 + j * 16 + lr] : 0.0f;

#pragma unroll
    for (int fi = 0; fi < 4; fi++) {
        const int row = rowBase + wm * 64 + fi * 16 + lc * 4;
#pragma unroll
        for (int fj = 0; fj < 4; fj++) {
            const int col = colBase + wn * 64 + fj * 16 + lr;
#pragma unroll
            for (int r = 0; r < 4; r++) {
                float v = acc[fi][fj][r] * alpha + bval[fj];
                if constexpr (EPI == 1) v = fast_gelu(v);
                if constexpr (EPI == 2) v += resid[(size_t)(row + r) * ldc + col];
                Cout[(size_t)(row + r) * ldc + col] = (OutT)v;
            }
        }
    }
}

// ---------------------------------------------------------------------------
// LayerNorm over last dim (C=1024), fp32 in -> bf16 out. One block per row.
// ---------------------------------------------------------------------------
__launch_bounds__(256)
__global__ void ln_kernel(const float* __restrict__ x, const float* __restrict__ g,
                          const float* __restrict__ b, bf16* __restrict__ out) {
    __shared__ float red[4];
    const int row = blockIdx.x;
    const int tid = threadIdx.x;
    const float4* xr = (const float4*)(x + (size_t)row * C_DIM);
    float4 v = xr[tid];
    float s = v.x + v.y + v.z + v.w;
#pragma unroll
    for (int m = 32; m; m >>= 1) s += __shfl_xor(s, m, 64);
    if ((tid & 63) == 0) red[tid >> 6] = s;
    __syncthreads();
    const float mu = (red[0] + red[1] + red[2] + red[3]) * (1.0f / C_DIM);
    const float dx = v.x - mu, dy = v.y - mu, dz = v.z - mu, dw = v.w - mu;
    float q = dx * dx + dy * dy + dz * dz + dw * dw;
#pragma unroll
    for (int m = 32; m; m >>= 1) q += __shfl_xor(q, m, 64);
    __syncthreads();
    if ((tid & 63) == 0) red[tid >> 6] = q;
    __syncthreads();
    const float var = (red[0] + red[1] + red[2] + red[3]) * (1.0f / C_DIM);
    const float rs = rsqrtf(var + 1e-5f);
    const float4 gg = ((const float4*)g)[tid];
    const float4 bb = ((const float4*)b)[tid];
    bf16x4 o;
    o[0] = (bf16)(dx * rs * gg.x + bb.x);
    o[1] = (bf16)(dy * rs * gg.y + bb.y);
    o[2] = (bf16)(dz * rs * gg.z + bb.z);
    o[3] = (bf16)(dw * rs * gg.w + bb.w);
    ((bf16x4*)(out + (size_t)row * C_DIM))[tid] = o;
}

// ---------------------------------------------------------------------------
// Row softmax: S row (T=2048 bf16) -> P row (bf16). One block per row.
// ---------------------------------------------------------------------------
__launch_bounds__(256)
__global__ void softmax_kernel(const bf16* __restrict__ S, bf16* __restrict__ P) {
    __shared__ float red[4];
    const size_t base = (size_t)blockIdx.x * T_DIM;
    const int tid = threadIdx.x;
    bf16x8 sv = ((const bf16x8*)(S + base))[tid];
    float e[8];
#pragma unroll
    for (int i = 0; i < 8; i++) e[i] = (float)sv[i];
    float mx = e[0];
#pragma unroll
    for (int i = 1; i < 8; i++) mx = fmaxf(mx, e[i]);
#pragma unroll
    for (int m = 32; m; m >>= 1) mx = fmaxf(mx, __shfl_xor(mx, m, 64));
    if ((tid & 63) == 0) red[tid >> 6] = mx;
    __syncthreads();
    mx = fmaxf(fmaxf(red[0], red[1]), fmaxf(red[2], red[3]));
    float s = 0.0f;
#pragma unroll
    for (int i = 0; i < 8; i++) {
        e[i] = __expf(e[i] - mx);
        s += e[i];
    }
#pragma unroll
    for (int m = 32; m; m >>= 1) s += __shfl_xor(s, m, 64);
    __syncthreads();
    if ((tid & 63) == 0) red[tid >> 6] = s;
    __syncthreads();
    const float inv = 1.0f / (red[0] + red[1] + red[2] + red[3]);
    bf16x8 p;
#pragma unroll
    for (int i = 0; i < 8; i++) p[i] = (bf16)(e[i] * inv);
    ((bf16x8*)(P + base))[tid] = p;
}

// ---------------------------------------------------------------------------
// Merged transpose+convert for all 4 weight matrices (fp32 [R,Cc] -> bf16 [Cc,R]).
// ---------------------------------------------------------------------------
__global__ void transpose_f2b_all(const float* __restrict__ s0, bf16* __restrict__ d0,
                                  const float* __restrict__ s1, bf16* __restrict__ d1,
                                  const float* __restrict__ s2, bf16* __restrict__ d2,
                                  const float* __restrict__ s3, bf16* __restrict__ d3) {
    __shared__ float tile[32][33];
    int id = blockIdx.x;
    const float* src;
    bf16* dst;
    int R, Cc, local;
    if (id < 3072)       { src = s0; dst = d0; R = 1024; Cc = 3072; local = id; }
    else if (id < 4096)  { src = s1; dst = d1; R = 1024; Cc = 1024; local = id - 3072; }
    else if (id < 8192)  { src = s2; dst = d2; R = 1024; Cc = 4096; local = id - 4096; }
    else                 { src = s3; dst = d3; R = 4096; Cc = 1024; local = id - 8192; }
    const int tilesX = Cc >> 5;
    const int bx = (local % tilesX) * 32;
    const int by = (local / tilesX) * 32;
    const int tx = threadIdx.x, ty = threadIdx.y;
    for (int i = ty; i < 32; i += 8)
        tile[i][tx] = src[(size_t)(by + i) * Cc + bx + tx];
    __syncthreads();
    for (int i = ty; i < 32; i += 8)
        dst[(size_t)(bx + i) * R + by + tx] = (bf16)tile[tx][i];
}

// Transpose bf16 [R, Cc] (ld=ldsrc) -> bf16 [Cc, R] (ld=R), batched via z.
__global__ void transpose_b2b(const bf16* __restrict__ src, int ldsrc, long long sstride,
                              bf16* __restrict__ dst, long long dstride, int R) {
    __shared__ bf16 tile[32][33];
    src += (long long)blockIdx.z * sstride;
    dst += (long long)blockIdx.z * dstride;
    const int bx = blockIdx.x * 32;
    const int by = blockIdx.y * 32;
    const int tx = threadIdx.x, ty = threadIdx.y;
    for (int i = ty; i < 32; i += 8)
        tile[i][tx] = src[(size_t)(by + i) * ldsrc + bx + tx];
    __syncthreads();
    for (int i = ty; i < 32; i += 8)
        dst[(size_t)(bx + i) * R + by + tx] = tile[tx][i];
}

// ---------------------------------------------------------------------------
extern "C" void kernel_launch(void* const* d_in, const int* in_sizes, int n_in,
                              void* d_out, int out_size, void* d_ws, size_t ws_size,
                              hipStream_t stream) {
    const float* x      = (const float*)d_in[0];
    const float* ln1_g  = (const float*)d_in[1];
    const float* ln1_b  = (const float*)d_in[2];
    const float* w_attn = (const float*)d_in[3];
    const float* b_attn = (const float*)d_in[4];
    const float* w_proj = (const float*)d_in[5];
    const float* b_proj = (const float*)d_in[6];
    const float* ln2_g  = (const float*)d_in[7];
    const float* ln2_b  = (const float*)d_in[8];
    const float* w_fc   = (const float*)d_in[9];
    const float* b_fc   = (const float*)d_in[10];
    const float* w_mlp  = (const float*)d_in[11];
    const float* b_mlp  = (const float*)d_in[12];
    float* out = (float*)d_out;

    const int M = B_DIM * T_DIM;  // 8192

    char* base = (char*)d_ws;
    size_t off = 0;
    auto alloc = [&](size_t bytes) -> char* {
        char* p = base + off;
        off += (bytes + 255) & ~(size_t)255;
        return p;
    };
    bf16* wT_attn = (bf16*)alloc((size_t)3072 * 1024 * 2);
    bf16* wT_proj = (bf16*)alloc((size_t)1024 * 1024 * 2);
    bf16* wT_fc   = (bf16*)alloc((size_t)4096 * 1024 * 2);
    bf16* wT_mlp  = (bf16*)alloc((size_t)1024 * 4096 * 2);
    bf16* h       = (bf16*)alloc((size_t)M * 1024 * 2);        // h1, reused as h2
    bf16* qkv     = (bf16*)alloc((size_t)M * 3072 * 2);
    bf16* vT      = (bf16*)alloc((size_t)B_DIM * 1024 * 2048 * 2);
    bf16* S       = (bf16*)alloc((size_t)B_DIM * 2048 * 2048 * 2);
    bf16* P       = (bf16*)alloc((size_t)B_DIM * 2048 * 2048 * 2);
    bf16* y       = (bf16*)alloc((size_t)M * 1024 * 2);
    float* x2     = (float*)alloc((size_t)M * 1024 * 4);
    bf16* act     = (bf16*)S;  // alias: S+P dead after PV; 67MB needed, S+P = 67MB

    const dim3 tb(32, 8);

    // weight transpose+convert, all 4 in one launch
    transpose_f2b_all<<<12288, tb, 0, stream>>>(w_attn, wT_attn, w_proj, wT_proj,
                                                w_fc, wT_fc, w_mlp, wT_mlp);

    // h = LN1(x)
    ln_kernel<<<M, 256, 0, stream>>>(x, ln1_g, ln1_b, h);

    // qkv = h @ w_attn + b_attn   [8192, 3072]
    gemm8p<0, bf16><<<dim3(64, 24, 1), 256, 0, stream>>>(
        h, 1024, 0, wT_attn, 1024, 0, qkv, 3072, 0, b_attn, nullptr, 0, 1.0f, 1024);

    // vT[b] = v[b]^T   (v = qkv cols [2C,3C))
    transpose_b2b<<<dim3(1024 / 32, 2048 / 32, B_DIM), tb, 0, stream>>>(
        qkv + 2 * C_DIM, 3072, (long long)T_DIM * 3072, vT, (long long)C_DIM * T_DIM, T_DIM);

    // S[b] = q[b] @ k[b]^T * (1/32)   [2048, 2048] bf16
    gemm8p<0, bf16><<<dim3(16, 16, B_DIM), 256, 0, stream>>>(
        qkv, 3072, (long long)T_DIM * 3072,
        qkv + C_DIM, 3072, (long long)T_DIM * 3072,
        S, 2048, (long long)T_DIM * T_DIM, nullptr, nullptr, 0, 0.03125f, 1024);

    // P = softmax(S) rows
    softmax_kernel<<<B_DIM * T_DIM, 256, 0, stream>>>(S, P);

    // y[b] = P[b] @ v[b]   [2048, 1024] bf16
    gemm8p<0, bf16><<<dim3(16, 8, B_DIM), 256, 0, stream>>>(
        P, 2048, (long long)T_DIM * T_DIM,
        vT, 2048, (long long)C_DIM * T_DIM,
        y, 1024, (long long)T_DIM * C_DIM, nullptr, nullptr, 0, 1.0f, 2048);

    // x2 = y @ w_proj + b_proj + x   [8192, 1024] fp32
    gemm8p<2, float><<<dim3(64, 8, 1), 256, 0, stream>>>(
        y, 1024, 0, wT_proj, 1024, 0, x2, 1024, 0, b_proj, x, 0, 1.0f, 1024);

    // h2 = LN2(x2)  (reuse h buffer)
    ln_kernel<<<M, 256, 0, stream>>>(x2, ln2_g, ln2_b, h);

    // act = gelu(h2 @ w_fc + b_fc)   [8192, 4096] bf16
    gemm8p<1, bf16><<<dim3(64, 32, 1), 256, 0, stream>>>(
        h, 1024, 0, wT_fc, 1024, 0, act, 4096, 0, b_fc, nullptr, 0, 1.0f, 1024);

    // out = act @ w_mlp_proj + b_mlp_proj + x2   [8192, 1024] fp32
    gemm8p<2, float><<<dim3(64, 8, 1), 256, 0, stream>>>(
        act, 4096, 0, wT_mlp, 4096, 0, out, 1024, 0, b_mlp, x2, 0, 1.0f, 4096);
}

// Round 7
// 516.277 us; speedup vs baseline: 1.0942x; 1.0002x over previous
//
#include <hip/hip_runtime.h>

typedef __bf16 bf16;
typedef bf16 bf16x8 __attribute__((ext_vector_type(8)));
typedef bf16 bf16x4 __attribute__((ext_vector_type(4)));
typedef float f32x4 __attribute__((ext_vector_type(4)));

#define C_DIM 1024
#define T_DIM 2048
#define B_DIM 4
#define H_DIM 4096

// ---------------------------------------------------------------------------
// async global -> LDS, 16B per lane. LDS dest is wave-uniform base + lane*16.
// ---------------------------------------------------------------------------
__device__ inline void gld_lds16(const bf16* g, bf16* l) {
    __builtin_amdgcn_global_load_lds(
        (const __attribute__((address_space(1))) unsigned int*)g,
        (__attribute__((address_space(3))) unsigned int*)l,
        16, 0, 0);
}

// fast tanh-gelu: u * sigmoid(1.5957692*u + 0.07135481*u^3)
__device__ inline float fast_gelu(float u) {
    float k2 = 1.5957691216057308f * u + 0.07135480895843475f * u * u * u;
    float t = __expf(-k2);
    return u * __builtin_amdgcn_rcpf(1.0f + t);
}

// ---------------------------------------------------------------------------
// 5-slot-ring 128x128 GEMM: C = alpha*A[M,K]@Bt[N,K]^T (+bias)(+gelu|+resid|vT)
//
// BM=BN=128, 4 waves (2x2), 256 threads, wave tile 64x64, MFMA 16x16x32 bf16.
// One phase = one 32-wide k-step; LDS ring of FIVE k-slots (A[5][128][32] +
// B[5][128][32] = 80KB) -> 2 blocks/CU.
//
// R6 audit: phase-slot 1772cyc vs MFMA 155 + LDS ~770; the ~800cyc residue is
// a staging-latency stall: in-flight gld window (8-12KB/block) < BW*latency
// (~28KB/CU). Fix = deeper ring: stage-ahead 4 phases, steady vmcnt(12)
// -> 24-32KB/CU in flight.
//
// Phase p: { ds_read slot(p%5) frags | stage k-step p+4 -> slot((p+4)%5) |
//            BAR1 | setprio(1) 16xMFMA setprio(0) | VMC(12) | BAR2 }
// VMC at phase BOTTOM (m201 placement) makes publication EXACT:
//   VMC(12)@p: outstanding = stages {p,p-1,p-2} -> proves stages <= p-3
//   landed; BAR2(p) publishes to all waves; read@p+1 needs stage@(p+1)-4
//   = p-3. Exactly sufficient, race-free.
// WAR: stage@p overwrites slot read @p-1; reads complete before MMA(p-1) <
// BAR2(p-1) < stage@p issue. Safe for all waves via the barrier.
// Tail (no stage in last 4 phases): VMC 8/4/0 at phases NP-4/NP-3/NP-2
// (each proves the next phase's read slot landed for ALL waves), none at NP-1.
//
// XOR swizzle (verified R2: SQ_LDS_BANK_CONFLICT = 0): 16B chunk c of row r
// at slot c ^ ((r>>1)&3); read chunk = lc ^ ((lr>>1)&3) (lane-only, folds
// into base); gld_lds dest LINEAR, global SOURCE chunk pre-swizzled.
// NO XCD swizzle (R3: 3.6x FETCH blowup).
//
// EPI: 0 = alpha*acc+bias -> OutT ; 1 = gelu ; 2 = +bias+resid(f32)
//      3 = qkv-with-vT: cols >= 2048 written TRANSPOSED to vT (resid param
//          reinterpreted as bf16* vT [B][1024][2048]) - kills transpose_b2b.
// ---------------------------------------------------------------------------
template <int EPI, typename OutT>
__launch_bounds__(256, 2)
__global__ void gemm8p(const bf16* __restrict__ A, int lda, long long sA,
                       const bf16* __restrict__ Bt, int ldb, long long sB,
                       OutT* __restrict__ Cout, int ldc, long long sC,
                       const float* __restrict__ bias,
                       const float* __restrict__ resid, long long sR,
                       float alpha, int K) {
    const int z = blockIdx.z;
    A += (long long)z * sA;
    Bt += (long long)z * sB;
    Cout += (long long)z * sC;
    if (EPI == 2 && resid) resid += (long long)z * sR;

    const int rowBase = blockIdx.x * 128;
    const int colBase = blockIdx.y * 128;

    __shared__ __align__(16) bf16 As[5 * 128 * 32];
    __shared__ __align__(16) bf16 Bs[5 * 128 * 32];

    const int tid = threadIdx.x;
    const int w = tid >> 6;
    const int lane = tid & 63;
    const int wm = w >> 1, wn = w & 1;
    const int lr = lane & 15, lc = lane >> 4;

    // staging: lane covers (row = tid>>2 in 0..63, swizzled 16B chunk);
    // second gld per slot covers rows 64..127 (swizzle row-invariant mod 8)
    const int gchunk = (tid & 3) ^ ((tid >> 3) & 3);
    const bf16* Ag = A + (size_t)(rowBase + (tid >> 2)) * lda + gchunk * 8;
    const bf16* Bg = Bt + (size_t)(colBase + (tid >> 2)) * ldb + gchunk * 8;
    const size_t ldaL = (size_t)lda, ldbL = (size_t)ldb;
    bf16* AsW = As + w * 512;   // wave slice inside each staged 4KB half-slab
    bf16* BsW = Bs + w * 512;

    // fragment read bases (element offsets); read chunk XOR folds into base
    const int rchunk = lc ^ ((lr >> 1) & 3);
    const int aBase = wm * 2048 + lr * 32 + rchunk * 8;   // + slotoff + i*512
    const int bBase = wn * 2048 + lr * 32 + rchunk * 8;

// stage k-step tau into ring slot at element-offset so (4 gld_lds)
#define STAGE(so, tau) do {                                                \
        const bf16* _ga = Ag + (size_t)(tau) * 32;                         \
        bf16* _la = AsW + (so);                                            \
        gld_lds16(_ga, _la);                                               \
        gld_lds16(_ga + 64 * ldaL, _la + 2048);                            \
        const bf16* _gb = Bg + (size_t)(tau) * 32;                         \
        bf16* _lb = BsW + (so);                                            \
        gld_lds16(_gb, _lb);                                               \
        gld_lds16(_gb + 64 * ldbL, _lb + 2048);                            \
    } while (0)

#define LOAD_AB(ro) do {                                                   \
        _Pragma("unroll")                                                  \
        for (int i = 0; i < 4; i++)                                        \
            af[i] = *(const bf16x8*)(As + aBase + (ro) + i * 512);         \
        _Pragma("unroll")                                                  \
        for (int j = 0; j < 4; j++)                                        \
            bfv[j] = *(const bf16x8*)(Bs + bBase + (ro) + j * 512);        \
    } while (0)

#define MMAALL() do {                                                      \
        __builtin_amdgcn_s_setprio(1);                                     \
        _Pragma("unroll")                                                  \
        for (int i = 0; i < 4; i++)                                        \
            _Pragma("unroll")                                              \
            for (int j = 0; j < 4; j++)                                    \
                acc[i][j] = __builtin_amdgcn_mfma_f32_16x16x32_bf16(       \
                    af[i], bfv[j], acc[i][j], 0, 0, 0);                    \
        __builtin_amdgcn_s_setprio(0);                                     \
    } while (0)

#define BAR() __builtin_amdgcn_s_barrier()
#define VMC(n) asm volatile("s_waitcnt vmcnt(" #n ")" ::: "memory")
#define ROT(x) x = (x == 16384) ? 0 : x + 4096

    f32x4 acc[4][4] = {};
    bf16x8 af[4], bfv[4];

    const int NP = K >> 5;  // 32-wide k-steps; K in {1024,2048,4096} -> NP >= 32

    // ---- prologue: stage k-steps 0..3 into slots 0..3 (16 glds) ----
    STAGE(0, 0);
    STAGE(4096, 1);
    STAGE(8192, 2);
    STAGE(12288, 3);
    VMC(12);   // own k-step-0 landed
    BAR();     // all waves' k-step-0 landed

    int roff = 0, soff = 16384;

    for (int p = 0; p < NP - 4; ++p) {
        LOAD_AB(roff);
        STAGE(soff, p + 4);
        BAR();
        MMAALL();
        VMC(12);   // proves stages <= p-3 landed; BAR2 publishes
        BAR();
        ROT(roff); ROT(soff);
    }

    // ---- tail: 4 phases, no staging; ladder proves next read for ALL waves
    LOAD_AB(roff);              // phase NP-4
    BAR(); MMAALL();
    VMC(8); BAR(); ROT(roff);

    LOAD_AB(roff);              // phase NP-3
    BAR(); MMAALL();
    VMC(4); BAR(); ROT(roff);

    LOAD_AB(roff);              // phase NP-2
    BAR(); MMAALL();
    VMC(0); BAR(); ROT(roff);

    LOAD_AB(roff);              // phase NP-1
    BAR(); MMAALL();

#undef STAGE
#undef LOAD_AB
#undef MMAALL
#undef BAR
#undef VMC
#undef ROT

    // ---- epilogue. C/D layout (16x16x32): col = lane&15, row = (lane>>4)*4 + reg ----
    float bval[4];
#pragma unroll
    for (int j = 0; j < 4; j++)
        bval[j] = bias ? bias[colBase + wn * 64 + j * 16 + lr] : 0.0f;

    if constexpr (EPI == 3) {
        if (colBase >= 2048) {
            // v-columns: write transposed into vT [B][1024][2048]
            bf16* vt = (bf16*)resid;
#pragma unroll
            for (int fi = 0; fi < 4; fi++) {
                const int row = rowBase + wm * 64 + fi * 16 + lc * 4;
                const int b = row >> 11, t0 = row & 2047;
#pragma unroll
                for (int fj = 0; fj < 4; fj++) {
                    const int vcol = colBase - 2048 + wn * 64 + fj * 16 + lr;
                    bf16x4 pk;
#pragma unroll
                    for (int r = 0; r < 4; r++)
                        pk[r] = (bf16)(acc[fi][fj][r] * alpha + bval[fj]);
                    *(bf16x4*)(vt + ((size_t)b * 1024 + vcol) * 2048 + t0) = pk;
                }
            }
            return;
        }
    }

#pragma unroll
    for (int fi = 0; fi < 4; fi++) {
        const int row = rowBase + wm * 64 + fi * 16 + lc * 4;
#pragma unroll
        for (int fj = 0; fj < 4; fj++) {
            const int col = colBase + wn * 64 + fj * 16 + lr;
#pragma unroll
            for (int r = 0; r < 4; r++) {
                float v = acc[fi][fj][r] * alpha + bval[fj];
                if constexpr (EPI == 1) v = fast_gelu(v);
                if constexpr (EPI == 2) v += resid[(size_t)(row + r) * ldc + col];
                Cout[(size_t)(row + r) * ldc + col] = (OutT)v;
            }
        }
    }
}

// ---------------------------------------------------------------------------
// LayerNorm over last dim (C=1024), fp32 in -> bf16 out. One block per row.
// ---------------------------------------------------------------------------
__launch_bounds__(256)
__global__ void ln_kernel(const float* __restrict__ x, const float* __restrict__ g,
                          const float* __restrict__ b, bf16* __restrict__ out) {
    __shared__ float red[4];
    const int row = blockIdx.x;
    const int tid = threadIdx.x;
    const float4* xr = (const float4*)(x + (size_t)row * C_DIM);
    float4 v = xr[tid];
    float s = v.x + v.y + v.z + v.w;
#pragma unroll
    for (int m = 32; m; m >>= 1) s += __shfl_xor(s, m, 64);
    if ((tid & 63) == 0) red[tid >> 6] = s;
    __syncthreads();
    const float mu = (red[0] + red[1] + red[2] + red[3]) * (1.0f / C_DIM);
    const float dx = v.x - mu, dy = v.y - mu, dz = v.z - mu, dw = v.w - mu;
    float q = dx * dx + dy * dy + dz * dz + dw * dw;
#pragma unroll
    for (int m = 32; m; m >>= 1) q += __shfl_xor(q, m, 64);
    __syncthreads();
    if ((tid & 63) == 0) red[tid >> 6] = q;
    __syncthreads();
    const float var = (red[0] + red[1] + red[2] + red[3]) * (1.0f / C_DIM);
    const float rs = rsqrtf(var + 1e-5f);
    const float4 gg = ((const float4*)g)[tid];
    const float4 bb = ((const float4*)b)[tid];
    bf16x4 o;
    o[0] = (bf16)(dx * rs * gg.x + bb.x);
    o[1] = (bf16)(dy * rs * gg.y + bb.y);
    o[2] = (bf16)(dz * rs * gg.z + bb.z);
    o[3] = (bf16)(dw * rs * gg.w + bb.w);
    ((bf16x4*)(out + (size_t)row * C_DIM))[tid] = o;
}

// ---------------------------------------------------------------------------
// Row softmax: S row (T=2048 bf16) -> P row (bf16). One block per row.
// ---------------------------------------------------------------------------
__launch_bounds__(256)
__global__ void softmax_kernel(const bf16* __restrict__ S, bf16* __restrict__ P) {
    __shared__ float red[4];
    const size_t base = (size_t)blockIdx.x * T_DIM;
    const int tid = threadIdx.x;
    bf16x8 sv = ((const bf16x8*)(S + base))[tid];
    float e[8];
#pragma unroll
    for (int i = 0; i < 8; i++) e[i] = (float)sv[i];
    float mx = e[0];
#pragma unroll
    for (int i = 1; i < 8; i++) mx = fmaxf(mx, e[i]);
#pragma unroll
    for (int m = 32; m; m >>= 1) mx = fmaxf(mx, __shfl_xor(mx, m, 64));
    if ((tid & 63) == 0) red[tid >> 6] = mx;
    __syncthreads();
    mx = fmaxf(fmaxf(red[0], red[1]), fmaxf(red[2], red[3]));
    float s = 0.0f;
#pragma unroll
    for (int i = 0; i < 8; i++) {
        e[i] = __expf(e[i] - mx);
        s += e[i];
    }
#pragma unroll
    for (int m = 32; m; m >>= 1) s += __shfl_xor(s, m, 64);
    __syncthreads();
    if ((tid & 63) == 0) red[tid >> 6] = s;
    __syncthreads();
    const float inv = 1.0f / (red[0] + red[1] + red[2] + red[3]);
    bf16x8 p;
#pragma unroll
    for (int i = 0; i < 8; i++) p[i] = (bf16)(e[i] * inv);
    ((bf16x8*)(P + base))[tid] = p;
}

// ---------------------------------------------------------------------------
// Merged transpose+convert for all 4 weight matrices (fp32 [R,Cc] -> bf16 [Cc,R]).
// ---------------------------------------------------------------------------
__global__ void transpose_f2b_all(const float* __restrict__ s0, bf16* __restrict__ d0,
                                  const float* __restrict__ s1, bf16* __restrict__ d1,
                                  const float* __restrict__ s2, bf16* __restrict__ d2,
                                  const float* __restrict__ s3, bf16* __restrict__ d3) {
    __shared__ float tile[32][33];
    int id = blockIdx.x;
    const float* src;
    bf16* dst;
    int R, Cc, local;
    if (id < 3072)       { src = s0; dst = d0; R = 1024; Cc = 3072; local = id; }
    else if (id < 4096)  { src = s1; dst = d1; R = 1024; Cc = 1024; local = id - 3072; }
    else if (id < 8192)  { src = s2; dst = d2; R = 1024; Cc = 4096; local = id - 4096; }
    else                 { src = s3; dst = d3; R = 4096; Cc = 1024; local = id - 8192; }
    const int tilesX = Cc >> 5;
    const int bx = (local % tilesX) * 32;
    const int by = (local / tilesX) * 32;
    const int tx = threadIdx.x, ty = threadIdx.y;
    for (int i = ty; i < 32; i += 8)
        tile[i][tx] = src[(size_t)(by + i) * Cc + bx + tx];
    __syncthreads();
    for (int i = ty; i < 32; i += 8)
        dst[(size_t)(bx + i) * R + by + tx] = (bf16)tile[tx][i];
}

// ---------------------------------------------------------------------------
extern "C" void kernel_launch(void* const* d_in, const int* in_sizes, int n_in,
                              void* d_out, int out_size, void* d_ws, size_t ws_size,
                              hipStream_t stream) {
    const float* x      = (const float*)d_in[0];
    const float* ln1_g  = (const float*)d_in[1];
    const float* ln1_b  = (const float*)d_in[2];
    const float* w_attn = (const float*)d_in[3];
    const float* b_attn = (const float*)d_in[4];
    const float* w_proj = (const float*)d_in[5];
    const float* b_proj = (const float*)d_in[6];
    const float* ln2_g  = (const float*)d_in[7];
    const float* ln2_b  = (const float*)d_in[8];
    const float* w_fc   = (const float*)d_in[9];
    const float* b_fc   = (const float*)d_in[10];
    const float* w_mlp  = (const float*)d_in[11];
    const float* b_mlp  = (const float*)d_in[12];
    float* out = (float*)d_out;

    const int M = B_DIM * T_DIM;  // 8192

    char* base = (char*)d_ws;
    size_t off = 0;
    auto alloc = [&](size_t bytes) -> char* {
        char* p = base + off;
        off += (bytes + 255) & ~(size_t)255;
        return p;
    };
    bf16* wT_attn = (bf16*)alloc((size_t)3072 * 1024 * 2);
    bf16* wT_proj = (bf16*)alloc((size_t)1024 * 1024 * 2);
    bf16* wT_fc   = (bf16*)alloc((size_t)4096 * 1024 * 2);
    bf16* wT_mlp  = (bf16*)alloc((size_t)1024 * 4096 * 2);
    bf16* h       = (bf16*)alloc((size_t)M * 1024 * 2);        // h1, reused as h2
    bf16* qkv     = (bf16*)alloc((size_t)M * 3072 * 2);
    bf16* vT      = (bf16*)alloc((size_t)B_DIM * 1024 * 2048 * 2);
    bf16* S       = (bf16*)alloc((size_t)B_DIM * 2048 * 2048 * 2);
    bf16* P       = (bf16*)alloc((size_t)B_DIM * 2048 * 2048 * 2);
    bf16* y       = (bf16*)alloc((size_t)M * 1024 * 2);
    float* x2     = (float*)alloc((size_t)M * 1024 * 4);
    bf16* act     = (bf16*)S;  // alias: S+P dead after PV; 67MB needed, S+P = 67MB

    const dim3 tb(32, 8);

    // weight transpose+convert, all 4 in one launch
    transpose_f2b_all<<<12288, tb, 0, stream>>>(w_attn, wT_attn, w_proj, wT_proj,
                                                w_fc, wT_fc, w_mlp, wT_mlp);

    // h = LN1(x)
    ln_kernel<<<M, 256, 0, stream>>>(x, ln1_g, ln1_b, h);

    // qkv = h @ w_attn + b_attn  [8192,3072]; v-cols written transposed to vT
    gemm8p<3, bf16><<<dim3(64, 24, 1), 256, 0, stream>>>(
        h, 1024, 0, wT_attn, 1024, 0, qkv, 3072, 0, b_attn,
        (const float*)vT, 0, 1.0f, 1024);

    // S[b] = q[b] @ k[b]^T * (1/32)   [2048, 2048] bf16
    gemm8p<0, bf16><<<dim3(16, 16, B_DIM), 256, 0, stream>>>(
        qkv, 3072, (long long)T_DIM * 3072,
        qkv + C_DIM, 3072, (long long)T_DIM * 3072,
        S, 2048, (long long)T_DIM * T_DIM, nullptr, nullptr, 0, 0.03125f, 1024);

    // P = softmax(S) rows
    softmax_kernel<<<B_DIM * T_DIM, 256, 0, stream>>>(S, P);

    // y[b] = P[b] @ v[b]   [2048, 1024] bf16
    gemm8p<0, bf16><<<dim3(16, 8, B_DIM), 256, 0, stream>>>(
        P, 2048, (long long)T_DIM * T_DIM,
        vT, 2048, (long long)C_DIM * T_DIM,
        y, 1024, (long long)T_DIM * C_DIM, nullptr, nullptr, 0, 1.0f, 2048);

    // x2 = y @ w_proj + b_proj + x   [8192, 1024] fp32
    gemm8p<2, float><<<dim3(64, 8, 1), 256, 0, stream>>>(
        y, 1024, 0, wT_proj, 1024, 0, x2, 1024, 0, b_proj, x, 0, 1.0f, 1024);

    // h2 = LN2(x2)  (reuse h buffer)
    ln_kernel<<<M, 256, 0, stream>>>(x2, ln2_g, ln2_b, h);

    // act = gelu(h2 @ w_fc + b_fc)   [8192, 4096] bf16
    gemm8p<1, bf16><<<dim3(64, 32, 1), 256, 0, stream>>>(
        h, 1024, 0, wT_fc, 1024, 0, act, 4096, 0, b_fc, nullptr, 0, 1.0f, 1024);

    // out = act @ w_mlp_proj + b_mlp_proj + x2   [8192, 1024] fp32
    gemm8p<2, float><<<dim3(64, 8, 1), 256, 0, stream>>>(
        act, 4096, 0, wT_mlp, 4096, 0, out, 1024, 0, b_mlp, x2, 0, 1.0f, 4096);
}

// Round 8
// 507.345 us; speedup vs baseline: 1.1135x; 1.0176x over previous
//
#include <hip/hip_runtime.h>

typedef __bf16 bf16;
typedef bf16 bf16x8 __attribute__((ext_vector_type(8)));
typedef bf16 bf16x4 __attribute__((ext_vector_type(4)));
typedef float f32x4 __attribute__((ext_vector_type(4)));

#define C_DIM 1024
#define T_DIM 2048
#define B_DIM 4
#define H_DIM 4096

// ---------------------------------------------------------------------------
// async global -> LDS, 16B per lane. LDS dest is wave-uniform base + lane*16.
// ---------------------------------------------------------------------------
__device__ inline void gld_lds16(const bf16* g, bf16* l) {
    __builtin_amdgcn_global_load_lds(
        (const __attribute__((address_space(1))) unsigned int*)g,
        (__attribute__((address_space(3))) unsigned int*)l,
        16, 0, 0);
}

// fast tanh-gelu: u * sigmoid(1.5957692*u + 0.07135481*u^3)
__device__ inline float fast_gelu(float u) {
    float k2 = 1.5957691216057308f * u + 0.07135480895843475f * u * u * u;
    float t = __expf(-k2);
    return u * __builtin_amdgcn_rcpf(1.0f + t);
}

// ---------------------------------------------------------------------------
// 256x128 GEMM, wave tile 128x64: C = alpha*A@Bt^T (+bias)(+gelu|+resid|vT)
//
// R7 post-mortem: R6/R7 identical => kernel sits at the serial LDS-BW+MFMA
// floor (per block-phase: 48KB LDS @85B/cyc = 565cyc + MFMA 258cyc ~= 886
// measured). The lever is LDS BYTES PER FLOP, i.e. wave-tile AREA.
//
// Geometry: BM=256, BN=128, 4 waves (2x2), 256 threads, wave tile 128x64
// (8x4 fragments of 16x16x32, 32 MFMA/phase/wave). Per k=32 phase:
// reads 4x12KB + writes 24KB = 72KB LDS for 2.1 MFLOP = 29.2 FLOP/B
// (64x64 tile was 21.8). LDS ring of 3 k-slots (A[256][32]=16KB +
// B[128][32]=8KB each) = 72KB -> 2 blocks/CU (stall-hider, R6-proven).
//
// Schedule (R6's, re-derived for ring-3 / 6 gld per phase):
//   phase p: { ds_read slot(p%3) frags | stage k-step p+2 | BAR |
//              setprio(1) 32xMFMA setprio(0) | VMC(6) | BAR }
//   VMC(6)@p bottom: outstanding = stages {p+1,p+2} (12) -> proves
//   stage(p+1) landed; BAR publishes to all waves; read@p+1 safe. Exact.
//   WAR: stage@p overwrites slot read @p-1, separated by BAR2(p-1).
//   Tail: phase NP-2 VMC(0), phase NP-1 nothing.
//
// XOR swizzle (verified R2: SQ_LDS_BANK_CONFLICT = 0): 16B chunk c of row r
// at slot c ^ ((r>>1)&3); read chunk = lc ^ ((lr>>1)&3) (lane-only: row =
// wm*128 + 16i + lr ≡ lr mod 8); gld_lds dest LINEAR, global SOURCE chunk
// pre-swizzled. NO XCD swizzle (R3: 3.6x FETCH blowup).
//
// EPI: 0 = alpha*acc+bias -> OutT ; 1 = gelu ; 2 = +bias+resid(f32)
//      3 = qkv-with-vT: cols >= 2048 written TRANSPOSED to vT (resid param
//          reinterpreted as bf16* vT [B][1024][2048]).
// ---------------------------------------------------------------------------
template <int EPI, typename OutT>
__launch_bounds__(256, 2)
__global__ void gemm8p(const bf16* __restrict__ A, int lda, long long sA,
                       const bf16* __restrict__ Bt, int ldb, long long sB,
                       OutT* __restrict__ Cout, int ldc, long long sC,
                       const float* __restrict__ bias,
                       const float* __restrict__ resid, long long sR,
                       float alpha, int K) {
    const int z = blockIdx.z;
    A += (long long)z * sA;
    Bt += (long long)z * sB;
    Cout += (long long)z * sC;
    if (EPI == 2 && resid) resid += (long long)z * sR;

    const int rowBase = blockIdx.x * 256;
    const int colBase = blockIdx.y * 128;

    __shared__ __align__(16) bf16 As[3 * 256 * 32];   // 48KB
    __shared__ __align__(16) bf16 Bs[3 * 128 * 32];   // 24KB

    const int tid = threadIdx.x;
    const int w = tid >> 6;
    const int lane = tid & 63;
    const int wm = w >> 1, wn = w & 1;
    const int lr = lane & 15, lc = lane >> 4;

    // staging: lane covers (row = tid>>2 in 0..63, swizzled 16B chunk);
    // extra gld sweeps cover rows +64/+128/+192 (swizzle row-invariant mod 8)
    const int gchunk = (tid & 3) ^ ((tid >> 3) & 3);
    const bf16* Ag = A + (size_t)(rowBase + (tid >> 2)) * lda + gchunk * 8;
    const bf16* Bg = Bt + (size_t)(colBase + (tid >> 2)) * ldb + gchunk * 8;
    const size_t ldaL = (size_t)lda, ldbL = (size_t)ldb;
    bf16* AsW = As + w * 512;   // wave slice inside each staged 4KB sweep
    bf16* BsW = Bs + w * 512;

    // fragment read bases (element offsets); read chunk XOR folds into base
    const int rchunk = lc ^ ((lr >> 1) & 3);
    const int aBase = wm * 4096 + lr * 32 + rchunk * 8;   // + slotoff + i*512
    const int bBase = wn * 2048 + lr * 32 + rchunk * 8;   // + slotoff + j*512

// stage k-step tau into A-slot offset sa / B-slot offset sb (6 gld_lds)
#define STAGE(sa, sb, tau) do {                                            \
        const bf16* _ga = Ag + (size_t)(tau) * 32;                         \
        bf16* _la = AsW + (sa);                                            \
        gld_lds16(_ga, _la);                                               \
        gld_lds16(_ga + 64 * ldaL, _la + 2048);                            \
        gld_lds16(_ga + 128 * ldaL, _la + 4096);                           \
        gld_lds16(_ga + 192 * ldaL, _la + 6144);                           \
        const bf16* _gb = Bg + (size_t)(tau) * 32;                         \
        bf16* _lb = BsW + (sb);                                            \
        gld_lds16(_gb, _lb);                                               \
        gld_lds16(_gb + 64 * ldbL, _lb + 2048);                            \
    } while (0)

#define LOAD_AB(ra, rb) do {                                               \
        _Pragma("unroll")                                                  \
        for (int i = 0; i < 8; i++)                                        \
            af[i] = *(const bf16x8*)(As + aBase + (ra) + i * 512);         \
        _Pragma("unroll")                                                  \
        for (int j = 0; j < 4; j++)                                        \
            bfv[j] = *(const bf16x8*)(Bs + bBase + (rb) + j * 512);        \
    } while (0)

#define MMAALL() do {                                                      \
        __builtin_amdgcn_s_setprio(1);                                     \
        _Pragma("unroll")                                                  \
        for (int i = 0; i < 8; i++)                                        \
            _Pragma("unroll")                                              \
            for (int j = 0; j < 4; j++)                                    \
                acc[i][j] = __builtin_amdgcn_mfma_f32_16x16x32_bf16(       \
                    af[i], bfv[j], acc[i][j], 0, 0, 0);                    \
        __builtin_amdgcn_s_setprio(0);                                     \
    } while (0)

#define BAR() __builtin_amdgcn_s_barrier()
#define VMC(n) asm volatile("s_waitcnt vmcnt(" #n ")" ::: "memory")
#define ROTA(x) x = (x == 16384) ? 0 : x + 8192
#define ROTB(x) x = (x == 8192) ? 0 : x + 4096

    f32x4 acc[8][4] = {};
    bf16x8 af[8], bfv[4];

    const int NP = K >> 5;  // 32-wide k-steps; K in {1024,2048,4096} -> NP >= 32

    // ---- prologue: stage k-steps 0,1 into slots 0,1 (12 glds) ----
    STAGE(0, 0, 0);
    STAGE(8192, 4096, 1);
    VMC(6);    // k-step 0 landed (k-step 1 in flight)
    BAR();     // published

    int rao = 0, rbo = 0, sao = 16384, sbo = 8192;

    for (int p = 0; p < NP - 2; ++p) {
        LOAD_AB(rao, rbo);
        STAGE(sao, sbo, p + 2);
        BAR();
        MMAALL();
        VMC(6);    // stages <= p+1 landed; BAR publishes
        BAR();
        ROTA(rao); ROTB(rbo); ROTA(sao); ROTB(sbo);
    }

    // ---- phase NP-2: no stage; drain ----
    LOAD_AB(rao, rbo);
    BAR();
    MMAALL();
    VMC(0);
    BAR();
    ROTA(rao); ROTB(rbo);

    // ---- phase NP-1 ----
    LOAD_AB(rao, rbo);
    BAR();
    MMAALL();

#undef STAGE
#undef LOAD_AB
#undef MMAALL
#undef BAR
#undef VMC
#undef ROTA
#undef ROTB

    // ---- epilogue. C/D layout (16x16x32): col = lane&15, row = (lane>>4)*4 + reg ----
    float bval[4];
#pragma unroll
    for (int j = 0; j < 4; j++)
        bval[j] = bias ? bias[colBase + wn * 64 + j * 16 + lr] : 0.0f;

    if constexpr (EPI == 3) {
        if (colBase >= 2048) {
            // v-columns: write transposed into vT [B][1024][2048]
            bf16* vt = (bf16*)resid;
#pragma unroll
            for (int fi = 0; fi < 8; fi++) {
                const int row = rowBase + wm * 128 + fi * 16 + lc * 4;
                const int b = row >> 11, t0 = row & 2047;
#pragma unroll
                for (int fj = 0; fj < 4; fj++) {
                    const int vcol = colBase - 2048 + wn * 64 + fj * 16 + lr;
                    bf16x4 pk;
#pragma unroll
                    for (int r = 0; r < 4; r++)
                        pk[r] = (bf16)(acc[fi][fj][r] * alpha + bval[fj]);
                    *(bf16x4*)(vt + ((size_t)b * 1024 + vcol) * 2048 + t0) = pk;
                }
            }
            return;
        }
    }

#pragma unroll
    for (int fi = 0; fi < 8; fi++) {
        const int row = rowBase + wm * 128 + fi * 16 + lc * 4;
#pragma unroll
        for (int fj = 0; fj < 4; fj++) {
            const int col = colBase + wn * 64 + fj * 16 + lr;
#pragma unroll
            for (int r = 0; r < 4; r++) {
                float v = acc[fi][fj][r] * alpha + bval[fj];
                if constexpr (EPI == 1) v = fast_gelu(v);
                if constexpr (EPI == 2) v += resid[(size_t)(row + r) * ldc + col];
                Cout[(size_t)(row + r) * ldc + col] = (OutT)v;
            }
        }
    }
}

// ---------------------------------------------------------------------------
// LayerNorm over last dim (C=1024), fp32 in -> bf16 out. One block per row.
// ---------------------------------------------------------------------------
__launch_bounds__(256)
__global__ void ln_kernel(const float* __restrict__ x, const float* __restrict__ g,
                          const float* __restrict__ b, bf16* __restrict__ out) {
    __shared__ float red[4];
    const int row = blockIdx.x;
    const int tid = threadIdx.x;
    const float4* xr = (const float4*)(x + (size_t)row * C_DIM);
    float4 v = xr[tid];
    float s = v.x + v.y + v.z + v.w;
#pragma unroll
    for (int m = 32; m; m >>= 1) s += __shfl_xor(s, m, 64);
    if ((tid & 63) == 0) red[tid >> 6] = s;
    __syncthreads();
    const float mu = (red[0] + red[1] + red[2] + red[3]) * (1.0f / C_DIM);
    const float dx = v.x - mu, dy = v.y - mu, dz = v.z - mu, dw = v.w - mu;
    float q = dx * dx + dy * dy + dz * dz + dw * dw;
#pragma unroll
    for (int m = 32; m; m >>= 1) q += __shfl_xor(q, m, 64);
    __syncthreads();
    if ((tid & 63) == 0) red[tid >> 6] = q;
    __syncthreads();
    const float var = (red[0] + red[1] + red[2] + red[3]) * (1.0f / C_DIM);
    const float rs = rsqrtf(var + 1e-5f);
    const float4 gg = ((const float4*)g)[tid];
    const float4 bb = ((const float4*)b)[tid];
    bf16x4 o;
    o[0] = (bf16)(dx * rs * gg.x + bb.x);
    o[1] = (bf16)(dy * rs * gg.y + bb.y);
    o[2] = (bf16)(dz * rs * gg.z + bb.z);
    o[3] = (bf16)(dw * rs * gg.w + bb.w);
    ((bf16x4*)(out + (size_t)row * C_DIM))[tid] = o;
}

// ---------------------------------------------------------------------------
// Row softmax: S row (T=2048 bf16) -> P row (bf16). One block per row.
// ---------------------------------------------------------------------------
__launch_bounds__(256)
__global__ void softmax_kernel(const bf16* __restrict__ S, bf16* __restrict__ P) {
    __shared__ float red[4];
    const size_t base = (size_t)blockIdx.x * T_DIM;
    const int tid = threadIdx.x;
    bf16x8 sv = ((const bf16x8*)(S + base))[tid];
    float e[8];
#pragma unroll
    for (int i = 0; i < 8; i++) e[i] = (float)sv[i];
    float mx = e[0];
#pragma unroll
    for (int i = 1; i < 8; i++) mx = fmaxf(mx, e[i]);
#pragma unroll
    for (int m = 32; m; m >>= 1) mx = fmaxf(mx, __shfl_xor(mx, m, 64));
    if ((tid & 63) == 0) red[tid >> 6] = mx;
    __syncthreads();
    mx = fmaxf(fmaxf(red[0], red[1]), fmaxf(red[2], red[3]));
    float s = 0.0f;
#pragma unroll
    for (int i = 0; i < 8; i++) {
        e[i] = __expf(e[i] - mx);
        s += e[i];
    }
#pragma unroll
    for (int m = 32; m; m >>= 1) s += __shfl_xor(s, m, 64);
    __syncthreads();
    if ((tid & 63) == 0) red[tid >> 6] = s;
    __syncthreads();
    const float inv = 1.0f / (red[0] + red[1] + red[2] + red[3]);
    bf16x8 p;
#pragma unroll
    for (int i = 0; i < 8; i++) p[i] = (bf16)(e[i] * inv);
    ((bf16x8*)(P + base))[tid] = p;
}

// ---------------------------------------------------------------------------
// Merged transpose+convert for all 4 weight matrices (fp32 [R,Cc] -> bf16 [Cc,R]).
// ---------------------------------------------------------------------------
__global__ void transpose_f2b_all(const float* __restrict__ s0, bf16* __restrict__ d0,
                                  const float* __restrict__ s1, bf16* __restrict__ d1,
                                  const float* __restrict__ s2, bf16* __restrict__ d2,
                                  const float* __restrict__ s3, bf16* __restrict__ d3) {
    __shared__ float tile[32][33];
    int id = blockIdx.x;
    const float* src;
    bf16* dst;
    int R, Cc, local;
    if (id < 3072)       { src = s0; dst = d0; R = 1024; Cc = 3072; local = id; }
    else if (id < 4096)  { src = s1; dst = d1; R = 1024; Cc = 1024; local = id - 3072; }
    else if (id < 8192)  { src = s2; dst = d2; R = 1024; Cc = 4096; local = id - 4096; }
    else                 { src = s3; dst = d3; R = 4096; Cc = 1024; local = id - 8192; }
    const int tilesX = Cc >> 5;
    const int bx = (local % tilesX) * 32;
    const int by = (local / tilesX) * 32;
    const int tx = threadIdx.x, ty = threadIdx.y;
    for (int i = ty; i < 32; i += 8)
        tile[i][tx] = src[(size_t)(by + i) * Cc + bx + tx];
    __syncthreads();
    for (int i = ty; i < 32; i += 8)
        dst[(size_t)(bx + i) * R + by + tx] = (bf16)tile[tx][i];
}

// ---------------------------------------------------------------------------
extern "C" void kernel_launch(void* const* d_in, const int* in_sizes, int n_in,
                              void* d_out, int out_size, void* d_ws, size_t ws_size,
                              hipStream_t stream) {
    const float* x      = (const float*)d_in[0];
    const float* ln1_g  = (const float*)d_in[1];
    const float* ln1_b  = (const float*)d_in[2];
    const float* w_attn = (const float*)d_in[3];
    const float* b_attn = (const float*)d_in[4];
    const float* w_proj = (const float*)d_in[5];
    const float* b_proj = (const float*)d_in[6];
    const float* ln2_g  = (const float*)d_in[7];
    const float* ln2_b  = (const float*)d_in[8];
    const float* w_fc   = (const float*)d_in[9];
    const float* b_fc   = (const float*)d_in[10];
    const float* w_mlp  = (const float*)d_in[11];
    const float* b_mlp  = (const float*)d_in[12];
    float* out = (float*)d_out;

    const int M = B_DIM * T_DIM;  // 8192

    char* base = (char*)d_ws;
    size_t off = 0;
    auto alloc = [&](size_t bytes) -> char* {
        char* p = base + off;
        off += (bytes + 255) & ~(size_t)255;
        return p;
    };
    bf16* wT_attn = (bf16*)alloc((size_t)3072 * 1024 * 2);
    bf16* wT_proj = (bf16*)alloc((size_t)1024 * 1024 * 2);
    bf16* wT_fc   = (bf16*)alloc((size_t)4096 * 1024 * 2);
    bf16* wT_mlp  = (bf16*)alloc((size_t)1024 * 4096 * 2);
    bf16* h       = (bf16*)alloc((size_t)M * 1024 * 2);        // h1, reused as h2
    bf16* qkv     = (bf16*)alloc((size_t)M * 3072 * 2);
    bf16* vT      = (bf16*)alloc((size_t)B_DIM * 1024 * 2048 * 2);
    bf16* S       = (bf16*)alloc((size_t)B_DIM * 2048 * 2048 * 2);
    bf16* P       = (bf16*)alloc((size_t)B_DIM * 2048 * 2048 * 2);
    bf16* y       = (bf16*)alloc((size_t)M * 1024 * 2);
    float* x2     = (float*)alloc((size_t)M * 1024 * 4);
    bf16* act     = (bf16*)S;  // alias: S+P dead after PV; 67MB needed, S+P = 67MB

    const dim3 tb(32, 8);

    // weight transpose+convert, all 4 in one launch
    transpose_f2b_all<<<12288, tb, 0, stream>>>(w_attn, wT_attn, w_proj, wT_proj,
                                                w_fc, wT_fc, w_mlp, wT_mlp);

    // h = LN1(x)
    ln_kernel<<<M, 256, 0, stream>>>(x, ln1_g, ln1_b, h);

    // qkv = h @ w_attn + b_attn  [8192,3072]; v-cols written transposed to vT
    gemm8p<3, bf16><<<dim3(32, 24, 1), 256, 0, stream>>>(
        h, 1024, 0, wT_attn, 1024, 0, qkv, 3072, 0, b_attn,
        (const float*)vT, 0, 1.0f, 1024);

    // S[b] = q[b] @ k[b]^T * (1/32)   [2048, 2048] bf16
    gemm8p<0, bf16><<<dim3(8, 16, B_DIM), 256, 0, stream>>>(
        qkv, 3072, (long long)T_DIM * 3072,
        qkv + C_DIM, 3072, (long long)T_DIM * 3072,
        S, 2048, (long long)T_DIM * T_DIM, nullptr, nullptr, 0, 0.03125f, 1024);

    // P = softmax(S) rows
    softmax_kernel<<<B_DIM * T_DIM, 256, 0, stream>>>(S, P);

    // y[b] = P[b] @ v[b]   [2048, 1024] bf16
    gemm8p<0, bf16><<<dim3(8, 8, B_DIM), 256, 0, stream>>>(
        P, 2048, (long long)T_DIM * T_DIM,
        vT, 2048, (long long)C_DIM * T_DIM,
        y, 1024, (long long)T_DIM * C_DIM, nullptr, nullptr, 0, 1.0f, 2048);

    // x2 = y @ w_proj + b_proj + x   [8192, 1024] fp32
    gemm8p<2, float><<<dim3(32, 8, 1), 256, 0, stream>>>(
        y, 1024, 0, wT_proj, 1024, 0, x2, 1024, 0, b_proj, x, 0, 1.0f, 1024);

    // h2 = LN2(x2)  (reuse h buffer)
    ln_kernel<<<M, 256, 0, stream>>>(x2, ln2_g, ln2_b, h);

    // act = gelu(h2 @ w_fc + b_fc)   [8192, 4096] bf16
    gemm8p<1, bf16><<<dim3(32, 32, 1), 256, 0, stream>>>(
        h, 1024, 0, wT_fc, 1024, 0, act, 4096, 0, b_fc, nullptr, 0, 1.0f, 1024);

    // out = act @ w_mlp_proj + b_mlp_proj + x2   [8192, 1024] fp32
    gemm8p<2, float><<<dim3(32, 8, 1), 256, 0, stream>>>(
        act, 4096, 0, wT_mlp, 4096, 0, out, 1024, 0, b_mlp, x2, 0, 1.0f, 4096);
}

// Round 9
// 481.029 us; speedup vs baseline: 1.1744x; 1.0547x over previous
//
#include <hip/hip_runtime.h>

typedef __bf16 bf16;
typedef bf16 bf16x8 __attribute__((ext_vector_type(8)));
typedef bf16 bf16x4 __attribute__((ext_vector_type(4)));
typedef float f32x4 __attribute__((ext_vector_type(4)));

#define C_DIM 1024
#define T_DIM 2048
#define B_DIM 4
#define H_DIM 4096

// ---------------------------------------------------------------------------
// async global -> LDS, 16B per lane. LDS dest is wave-uniform base + lane*16.
// ---------------------------------------------------------------------------
__device__ inline void gld_lds16(const bf16* g, bf16* l) {
    __builtin_amdgcn_global_load_lds(
        (const __attribute__((address_space(1))) unsigned int*)g,
        (__attribute__((address_space(3))) unsigned int*)l,
        16, 0, 0);
}

// fast tanh-gelu: u * sigmoid(1.5957692*u + 0.07135481*u^3)
__device__ inline float fast_gelu(float u) {
    float k2 = 1.5957691216057308f * u + 0.07135480895843475f * u * u * u;
    float t = __expf(-k2);
    return u * __builtin_amdgcn_rcpf(1.0f + t);
}

// ---------------------------------------------------------------------------
// BMx128 GEMM (BM template: 256 or 128), wave tile (BM/2)x64, 4 waves (2x2),
// 256 threads, MFMA 16x16x32 bf16, ring-3 LDS.
//
// R8 post-mortem: BM=256 grids of 256 blocks = 1 block/CU = 1 wave/SIMD ->
// LDS service and MFMA serialize PLUS ~400cyc exposed latency (Occupancy
// 10.4%, mlp 94us). Shapes with >=512 blocks (2 blocks/CU = 2 waves/SIMD)
// overlap fine. Fix: per-shape BM. BM=256 (72KB LDS, 29.2 FLOP/B) where
// grid >= 512; BM=128 (48KB, 21.8 FLOP/B) for N=1024 GEMMs so their grids
// are 512 -> 2 blocks/CU.
//
// Schedule (R8, BM-generalized; g = BM/64+2 gld per phase):
//   phase p: { ds_read slot(p%3) frags | stage k-step p+2 | BAR |
//              setprio(1) FM*4 MFMA setprio(0) | VMC(g) | BAR }
//   VMC(g)@p bottom leaves only stage(p+2) outstanding -> stage(p+1) landed;
//   BAR publishes; read@p+1 safe for all waves. WAR: stage@p overwrites the
//   slot read @p-1, separated by BAR2(p-1). Tail: VMC(0) at NP-2.
//
// XOR swizzle (verified R2: SQ_LDS_BANK_CONFLICT = 0): 16B chunk c of row r
// at slot c ^ ((r>>1)&3); read chunk = lc ^ ((lr>>1)&3) (lane-only: row =
// wm*(BM/2) + 16i + lr ≡ lr mod 8); gld_lds dest LINEAR, global SOURCE chunk
// pre-swizzled. NO XCD swizzle (R3: 3.6x FETCH blowup).
//
// EPI: 0 = alpha*acc+bias -> OutT ; 1 = gelu ; 2 = +bias+resid(f32)
//      3 = qkv-with-vT: cols >= 2048 written TRANSPOSED to vT (resid param
//          reinterpreted as bf16* vT [B][1024][2048]).
// ---------------------------------------------------------------------------
template <int EPI, typename OutT, int BM>
__launch_bounds__(256, 2)
__global__ void gemm8p(const bf16* __restrict__ A, int lda, long long sA,
                       const bf16* __restrict__ Bt, int ldb, long long sB,
                       OutT* __restrict__ Cout, int ldc, long long sC,
                       const float* __restrict__ bias,
                       const float* __restrict__ resid, long long sR,
                       float alpha, int K) {
    constexpr int FM = BM / 32;        // A fragments per wave (8 or 4)
    constexpr int ASLOT = BM * 32;     // A ring-slot elements (8192 or 4096)

    const int z = blockIdx.z;
    A += (long long)z * sA;
    Bt += (long long)z * sB;
    Cout += (long long)z * sC;
    if (EPI == 2 && resid) resid += (long long)z * sR;

    const int rowBase = blockIdx.x * BM;
    const int colBase = blockIdx.y * 128;

    __shared__ __align__(16) bf16 As[3 * BM * 32];    // 48KB or 24KB
    __shared__ __align__(16) bf16 Bs[3 * 128 * 32];   // 24KB

    const int tid = threadIdx.x;
    const int w = tid >> 6;
    const int lane = tid & 63;
    const int wm = w >> 1, wn = w & 1;
    const int lr = lane & 15, lc = lane >> 4;

    // staging: lane covers (row = tid>>2 in 0..63, swizzled 16B chunk);
    // extra gld sweeps cover rows +64(+128/+192) (swizzle row-invariant mod 8)
    const int gchunk = (tid & 3) ^ ((tid >> 3) & 3);
    const bf16* Ag = A + (size_t)(rowBase + (tid >> 2)) * lda + gchunk * 8;
    const bf16* Bg = Bt + (size_t)(colBase + (tid >> 2)) * ldb + gchunk * 8;
    const size_t ldaL = (size_t)lda, ldbL = (size_t)ldb;
    bf16* AsW = As + w * 512;   // wave slice inside each staged 4KB sweep
    bf16* BsW = Bs + w * 512;

    // fragment read bases (element offsets); read chunk XOR folds into base
    const int rchunk = lc ^ ((lr >> 1) & 3);
    const int aBase = wm * (FM * 512) + lr * 32 + rchunk * 8;
    const int bBase = wn * 2048 + lr * 32 + rchunk * 8;

// stage k-step tau into A-slot offset sa / B-slot offset sb
#define STAGE(sa, sb, tau) do {                                            \
        const bf16* _ga = Ag + (size_t)(tau) * 32;                         \
        bf16* _la = AsW + (sa);                                            \
        gld_lds16(_ga, _la);                                               \
        gld_lds16(_ga + 64 * ldaL, _la + 2048);                            \
        if constexpr (BM == 256) {                                         \
            gld_lds16(_ga + 128 * ldaL, _la + 4096);                       \
            gld_lds16(_ga + 192 * ldaL, _la + 6144);                       \
        }                                                                  \
        const bf16* _gb = Bg + (size_t)(tau) * 32;                         \
        bf16* _lb = BsW + (sb);                                            \
        gld_lds16(_gb, _lb);                                               \
        gld_lds16(_gb + 64 * ldbL, _lb + 2048);                            \
    } while (0)

#define LOAD_AB(ra, rb) do {                                               \
        _Pragma("unroll")                                                  \
        for (int i = 0; i < FM; i++)                                       \
            af[i] = *(const bf16x8*)(As + aBase + (ra) + i * 512);         \
        _Pragma("unroll")                                                  \
        for (int j = 0; j < 4; j++)                                        \
            bfv[j] = *(const bf16x8*)(Bs + bBase + (rb) + j * 512);        \
    } while (0)

#define MMAALL() do {                                                      \
        __builtin_amdgcn_s_setprio(1);                                     \
        _Pragma("unroll")                                                  \
        for (int i = 0; i < FM; i++)                                       \
            _Pragma("unroll")                                              \
            for (int j = 0; j < 4; j++)                                    \
                acc[i][j] = __builtin_amdgcn_mfma_f32_16x16x32_bf16(       \
                    af[i], bfv[j], acc[i][j], 0, 0, 0);                    \
        __builtin_amdgcn_s_setprio(0);                                     \
    } while (0)

#define BAR() __builtin_amdgcn_s_barrier()
#define VMCG() do {                                                        \
        if constexpr (BM == 256) asm volatile("s_waitcnt vmcnt(6)" ::: "memory"); \
        else                     asm volatile("s_waitcnt vmcnt(4)" ::: "memory"); \
    } while (0)
#define VMC0() asm volatile("s_waitcnt vmcnt(0)" ::: "memory")
#define ROTA(x) x = (x == 2 * ASLOT) ? 0 : x + ASLOT
#define ROTB(x) x = (x == 8192) ? 0 : x + 4096

    f32x4 acc[FM][4] = {};
    bf16x8 af[FM], bfv[4];

    const int NP = K >> 5;  // 32-wide k-steps; K in {1024,2048,4096} -> NP >= 32

    // ---- prologue: stage k-steps 0,1 into slots 0,1 ----
    STAGE(0, 0, 0);
    STAGE(ASLOT, 4096, 1);
    VMCG();    // k-step 0 landed (k-step 1 in flight)
    BAR();     // published

    int rao = 0, rbo = 0, sao = 2 * ASLOT, sbo = 8192;

    for (int p = 0; p < NP - 2; ++p) {
        LOAD_AB(rao, rbo);
        STAGE(sao, sbo, p + 2);
        BAR();
        MMAALL();
        VMCG();    // stages <= p+1 landed; BAR publishes
        BAR();
        ROTA(rao); ROTB(rbo); ROTA(sao); ROTB(sbo);
    }

    // ---- phase NP-2: no stage; drain ----
    LOAD_AB(rao, rbo);
    BAR();
    MMAALL();
    VMC0();
    BAR();
    ROTA(rao); ROTB(rbo);

    // ---- phase NP-1 ----
    LOAD_AB(rao, rbo);
    BAR();
    MMAALL();

#undef STAGE
#undef LOAD_AB
#undef MMAALL
#undef BAR
#undef VMCG
#undef VMC0
#undef ROTA
#undef ROTB

    // ---- epilogue. C/D layout (16x16x32): col = lane&15, row = (lane>>4)*4 + reg ----
    float bval[4];
#pragma unroll
    for (int j = 0; j < 4; j++)
        bval[j] = bias ? bias[colBase + wn * 64 + j * 16 + lr] : 0.0f;

    if constexpr (EPI == 3) {
        if (colBase >= 2048) {
            // v-columns: write transposed into vT [B][1024][2048]
            bf16* vt = (bf16*)resid;
#pragma unroll
            for (int fi = 0; fi < FM; fi++) {
                const int row = rowBase + wm * (BM / 2) + fi * 16 + lc * 4;
                const int b = row >> 11, t0 = row & 2047;
#pragma unroll
                for (int fj = 0; fj < 4; fj++) {
                    const int vcol = colBase - 2048 + wn * 64 + fj * 16 + lr;
                    bf16x4 pk;
#pragma unroll
                    for (int r = 0; r < 4; r++)
                        pk[r] = (bf16)(acc[fi][fj][r] * alpha + bval[fj]);
                    *(bf16x4*)(vt + ((size_t)b * 1024 + vcol) * 2048 + t0) = pk;
                }
            }
            return;
        }
    }

#pragma unroll
    for (int fi = 0; fi < FM; fi++) {
        const int row = rowBase + wm * (BM / 2) + fi * 16 + lc * 4;
#pragma unroll
        for (int fj = 0; fj < 4; fj++) {
            const int col = colBase + wn * 64 + fj * 16 + lr;
#pragma unroll
            for (int r = 0; r < 4; r++) {
                float v = acc[fi][fj][r] * alpha + bval[fj];
                if constexpr (EPI == 1) v = fast_gelu(v);
                if constexpr (EPI == 2) v += resid[(size_t)(row + r) * ldc + col];
                Cout[(size_t)(row + r) * ldc + col] = (OutT)v;
            }
        }
    }
}

// ---------------------------------------------------------------------------
// LayerNorm over last dim (C=1024), fp32 in -> bf16 out. One block per row.
// ---------------------------------------------------------------------------
__launch_bounds__(256)
__global__ void ln_kernel(const float* __restrict__ x, const float* __restrict__ g,
                          const float* __restrict__ b, bf16* __restrict__ out) {
    __shared__ float red[4];
    const int row = blockIdx.x;
    const int tid = threadIdx.x;
    const float4* xr = (const float4*)(x + (size_t)row * C_DIM);
    float4 v = xr[tid];
    float s = v.x + v.y + v.z + v.w;
#pragma unroll
    for (int m = 32; m; m >>= 1) s += __shfl_xor(s, m, 64);
    if ((tid & 63) == 0) red[tid >> 6] = s;
    __syncthreads();
    const float mu = (red[0] + red[1] + red[2] + red[3]) * (1.0f / C_DIM);
    const float dx = v.x - mu, dy = v.y - mu, dz = v.z - mu, dw = v.w - mu;
    float q = dx * dx + dy * dy + dz * dz + dw * dw;
#pragma unroll
    for (int m = 32; m; m >>= 1) q += __shfl_xor(q, m, 64);
    __syncthreads();
    if ((tid & 63) == 0) red[tid >> 6] = q;
    __syncthreads();
    const float var = (red[0] + red[1] + red[2] + red[3]) * (1.0f / C_DIM);
    const float rs = rsqrtf(var + 1e-5f);
    const float4 gg = ((const float4*)g)[tid];
    const float4 bb = ((const float4*)b)[tid];
    bf16x4 o;
    o[0] = (bf16)(dx * rs * gg.x + bb.x);
    o[1] = (bf16)(dy * rs * gg.y + bb.y);
    o[2] = (bf16)(dz * rs * gg.z + bb.z);
    o[3] = (bf16)(dw * rs * gg.w + bb.w);
    ((bf16x4*)(out + (size_t)row * C_DIM))[tid] = o;
}

// ---------------------------------------------------------------------------
// Row softmax: S row (T=2048 bf16) -> P row (bf16). One block per row.
// ---------------------------------------------------------------------------
__launch_bounds__(256)
__global__ void softmax_kernel(const bf16* __restrict__ S, bf16* __restrict__ P) {
    __shared__ float red[4];
    const size_t base = (size_t)blockIdx.x * T_DIM;
    const int tid = threadIdx.x;
    bf16x8 sv = ((const bf16x8*)(S + base))[tid];
    float e[8];
#pragma unroll
    for (int i = 0; i < 8; i++) e[i] = (float)sv[i];
    float mx = e[0];
#pragma unroll
    for (int i = 1; i < 8; i++) mx = fmaxf(mx, e[i]);
#pragma unroll
    for (int m = 32; m; m >>= 1) mx = fmaxf(mx, __shfl_xor(mx, m, 64));
    if ((tid & 63) == 0) red[tid >> 6] = mx;
    __syncthreads();
    mx = fmaxf(fmaxf(red[0], red[1]), fmaxf(red[2], red[3]));
    float s = 0.0f;
#pragma unroll
    for (int i = 0; i < 8; i++) {
        e[i] = __expf(e[i] - mx);
        s += e[i];
    }
#pragma unroll
    for (int m = 32; m; m >>= 1) s += __shfl_xor(s, m, 64);
    __syncthreads();
    if ((tid & 63) == 0) red[tid >> 6] = s;
    __syncthreads();
    const float inv = 1.0f / (red[0] + red[1] + red[2] + red[3]);
    bf16x8 p;
#pragma unroll
    for (int i = 0; i < 8; i++) p[i] = (bf16)(e[i] * inv);
    ((bf16x8*)(P + base))[tid] = p;
}

// ---------------------------------------------------------------------------
// Merged transpose+convert for all 4 weight matrices (fp32 [R,Cc] -> bf16 [Cc,R]).
// ---------------------------------------------------------------------------
__global__ void transpose_f2b_all(const float* __restrict__ s0, bf16* __restrict__ d0,
                                  const float* __restrict__ s1, bf16* __restrict__ d1,
                                  const float* __restrict__ s2, bf16* __restrict__ d2,
                                  const float* __restrict__ s3, bf16* __restrict__ d3) {
    __shared__ float tile[32][33];
    int id = blockIdx.x;
    const float* src;
    bf16* dst;
    int R, Cc, local;
    if (id < 3072)       { src = s0; dst = d0; R = 1024; Cc = 3072; local = id; }
    else if (id < 4096)  { src = s1; dst = d1; R = 1024; Cc = 1024; local = id - 3072; }
    else if (id < 8192)  { src = s2; dst = d2; R = 1024; Cc = 4096; local = id - 4096; }
    else                 { src = s3; dst = d3; R = 4096; Cc = 1024; local = id - 8192; }
    const int tilesX = Cc >> 5;
    const int bx = (local % tilesX) * 32;
    const int by = (local / tilesX) * 32;
    const int tx = threadIdx.x, ty = threadIdx.y;
    for (int i = ty; i < 32; i += 8)
        tile[i][tx] = src[(size_t)(by + i) * Cc + bx + tx];
    __syncthreads();
    for (int i = ty; i < 32; i += 8)
        dst[(size_t)(bx + i) * R + by + tx] = (bf16)tile[tx][i];
}

// ---------------------------------------------------------------------------
extern "C" void kernel_launch(void* const* d_in, const int* in_sizes, int n_in,
                              void* d_out, int out_size, void* d_ws, size_t ws_size,
                              hipStream_t stream) {
    const float* x      = (const float*)d_in[0];
    const float* ln1_g  = (const float*)d_in[1];
    const float* ln1_b  = (const float*)d_in[2];
    const float* w_attn = (const float*)d_in[3];
    const float* b_attn = (const float*)d_in[4];
    const float* w_proj = (const float*)d_in[5];
    const float* b_proj = (const float*)d_in[6];
    const float* ln2_g  = (const float*)d_in[7];
    const float* ln2_b  = (const float*)d_in[8];
    const float* w_fc   = (const float*)d_in[9];
    const float* b_fc   = (const float*)d_in[10];
    const float* w_mlp  = (const float*)d_in[11];
    const float* b_mlp  = (const float*)d_in[12];
    float* out = (float*)d_out;

    const int M = B_DIM * T_DIM;  // 8192

    char* base = (char*)d_ws;
    size_t off = 0;
    auto alloc = [&](size_t bytes) -> char* {
        char* p = base + off;
        off += (bytes + 255) & ~(size_t)255;
        return p;
    };
    bf16* wT_attn = (bf16*)alloc((size_t)3072 * 1024 * 2);
    bf16* wT_proj = (bf16*)alloc((size_t)1024 * 1024 * 2);
    bf16* wT_fc   = (bf16*)alloc((size_t)4096 * 1024 * 2);
    bf16* wT_mlp  = (bf16*)alloc((size_t)1024 * 4096 * 2);
    bf16* h       = (bf16*)alloc((size_t)M * 1024 * 2);        // h1, reused as h2
    bf16* qkv     = (bf16*)alloc((size_t)M * 3072 * 2);
    bf16* vT      = (bf16*)alloc((size_t)B_DIM * 1024 * 2048 * 2);
    bf16* S       = (bf16*)alloc((size_t)B_DIM * 2048 * 2048 * 2);
    bf16* P       = (bf16*)alloc((size_t)B_DIM * 2048 * 2048 * 2);
    bf16* y       = (bf16*)alloc((size_t)M * 1024 * 2);
    float* x2     = (float*)alloc((size_t)M * 1024 * 4);
    bf16* act     = (bf16*)S;  // alias: S+P dead after PV; 67MB needed, S+P = 67MB

    const dim3 tb(32, 8);

    // weight transpose+convert, all 4 in one launch
    transpose_f2b_all<<<12288, tb, 0, stream>>>(w_attn, wT_attn, w_proj, wT_proj,
                                                w_fc, wT_fc, w_mlp, wT_mlp);

    // h = LN1(x)
    ln_kernel<<<M, 256, 0, stream>>>(x, ln1_g, ln1_b, h);

    // qkv = h @ w_attn + b_attn  [8192,3072]; v-cols written transposed to vT
    gemm8p<3, bf16, 256><<<dim3(32, 24, 1), 256, 0, stream>>>(
        h, 1024, 0, wT_attn, 1024, 0, qkv, 3072, 0, b_attn,
        (const float*)vT, 0, 1.0f, 1024);

    // S[b] = q[b] @ k[b]^T * (1/32)   [2048, 2048] bf16   (512 blocks)
    gemm8p<0, bf16, 256><<<dim3(8, 16, B_DIM), 256, 0, stream>>>(
        qkv, 3072, (long long)T_DIM * 3072,
        qkv + C_DIM, 3072, (long long)T_DIM * 3072,
        S, 2048, (long long)T_DIM * T_DIM, nullptr, nullptr, 0, 0.03125f, 1024);

    // P = softmax(S) rows
    softmax_kernel<<<B_DIM * T_DIM, 256, 0, stream>>>(S, P);

    // y[b] = P[b] @ v[b]   [2048, 1024] bf16   (BM=128 -> 512 blocks)
    gemm8p<0, bf16, 128><<<dim3(16, 8, B_DIM), 256, 0, stream>>>(
        P, 2048, (long long)T_DIM * T_DIM,
        vT, 2048, (long long)C_DIM * T_DIM,
        y, 1024, (long long)T_DIM * C_DIM, nullptr, nullptr, 0, 1.0f, 2048);

    // x2 = y @ w_proj + b_proj + x   [8192, 1024] fp32   (BM=128 -> 512 blocks)
    gemm8p<2, float, 128><<<dim3(64, 8, 1), 256, 0, stream>>>(
        y, 1024, 0, wT_proj, 1024, 0, x2, 1024, 0, b_proj, x, 0, 1.0f, 1024);

    // h2 = LN2(x2)  (reuse h buffer)
    ln_kernel<<<M, 256, 0, stream>>>(x2, ln2_g, ln2_b, h);

    // act = gelu(h2 @ w_fc + b_fc)   [8192, 4096] bf16   (1024 blocks)
    gemm8p<1, bf16, 256><<<dim3(32, 32, 1), 256, 0, stream>>>(
        h, 1024, 0, wT_fc, 1024, 0, act, 4096, 0, b_fc, nullptr, 0, 1.0f, 1024);

    // out = act @ w_mlp_proj + b_mlp_proj + x2  [8192,1024] fp32  (BM=128 -> 512)
    gemm8p<2, float, 128><<<dim3(64, 8, 1), 256, 0, stream>>>(
        act, 4096, 0, wT_mlp, 4096, 0, out, 1024, 0, b_mlp, x2, 0, 1.0f, 4096);
}